// Round 12
// baseline (788.168 us; speedup 1.0000x reference)
//
#include <hip/hip_runtime.h>
#include <hip/hip_bf16.h>

#define NN 20000      // nodes
#define NE 640000     // edges
#define DIN 256
#define DM  128
#define ROWS 96       // rows per layer_k block (209 blocks -> single scheduling round)

typedef __hip_bfloat16 bf16;
typedef __attribute__((ext_vector_type(8))) short s8;     // 8 bf16 (4 VGPRs) MFMA frag
typedef __attribute__((ext_vector_type(4))) float f4;     // 4 f32 acc
typedef __attribute__((ext_vector_type(2))) float fl2;

__device__ __forceinline__ float bu2f_lo(unsigned u) { union {unsigned u; float f;} c; c.u = u << 16; return c.f; }
__device__ __forceinline__ float bu2f_hi(unsigned u) { union {unsigned u; float f;} c; c.u = u & 0xffff0000u; return c.f; }
__device__ __forceinline__ unsigned short f2bu(float f) { bf16 t = __float2bfloat16(f); return *reinterpret_cast<unsigned short*>(&t); }
__device__ __forceinline__ unsigned pk2(float lo, float hi) { return (unsigned)f2bu(lo) | ((unsigned)f2bu(hi) << 16); }
__device__ __forceinline__ unsigned addpk(unsigned a, unsigned b) {
    return pk2(bu2f_lo(a) + bu2f_lo(b), bu2f_hi(a) + bu2f_hi(b));
}
__device__ __forceinline__ void up8(uint4 u, float* f) {
    f[0] = bu2f_lo(u.x); f[1] = bu2f_hi(u.x);
    f[2] = bu2f_lo(u.y); f[3] = bu2f_hi(u.y);
    f[4] = bu2f_lo(u.z); f[5] = bu2f_hi(u.z);
    f[6] = bu2f_lo(u.w); f[7] = bu2f_hi(u.w);
}

// ---------------- fp8 e4m3 (OCP) helpers: HW cvt if available, exact bit fallback ----
#if defined(__has_builtin)
#if __has_builtin(__builtin_amdgcn_cvt_pk_f32_fp8) && __has_builtin(__builtin_amdgcn_cvt_pk_fp8_f32)
#define HW_FP8 1
#endif
#endif

__device__ __forceinline__ void fp8x4(unsigned u, float* o) {
#ifdef HW_FP8
    fl2 lo = __builtin_amdgcn_cvt_pk_f32_fp8((int)u, false);
    fl2 hi = __builtin_amdgcn_cvt_pk_f32_fp8((int)u, true);
    o[0] = lo[0]; o[1] = lo[1]; o[2] = hi[0]; o[3] = hi[1];
#else
#pragma unroll
    for (int i = 0; i < 4; ++i) {
        unsigned b = (u >> (8 * i)) & 0xffu;
        unsigned w = ((b & 0x80u) << 24) | ((b & 0x7fu) << 20);
        o[i] = __uint_as_float(w) * 1.3292279957849159e36f;   // x2^120
    }
#endif
}

__device__ __forceinline__ unsigned char f2fp8(float v) {
#ifdef HW_FP8
    int r = __builtin_amdgcn_cvt_pk_fp8_f32(v, 0.f, 0, false);
    return (unsigned char)(r & 0xff);
#else
    float a = fabsf(v);
    unsigned s = (__float_as_uint(v) >> 24) & 0x80u;
    a = fminf(a, 448.f);
    unsigned out;
    if (a < 0.0009765625f) {
        out = 0;
    } else if (a < 0.015625f) {
        int q = (int)(a * 512.f + 0.5f);
        out = (unsigned)q;
    } else {
        unsigned bits = __float_as_uint(a);
        int e = (int)((bits >> 23) & 0xff) - 127;
        unsigned m = bits & 0x7fffffu;
        unsigned mr = m + 0x7ffffu + ((m >> 20) & 1u);
        if (mr >> 23) { mr = 0; e += 1; } else mr >>= 20;
        if (e > 8) { e = 8; mr = 7; }
        out = ((unsigned)(e + 7) << 3) | (mr & 7u);
    }
    return (unsigned char)(out | s);
#endif
}

// ---------------- CSR build (dst-sorted edge list) ----------------
__global__ void hist_k(const int* __restrict__ dst, int* __restrict__ cnt, int E) {
    int e = blockIdx.x * 256 + threadIdx.x;
    if (e < E) atomicAdd(&cnt[dst[e]], 1);
}

__global__ void scan1_k(const int* __restrict__ cnt, int* __restrict__ part,
                        int* __restrict__ bsum, int n) {
    __shared__ int lds[1024];
    int b = blockIdx.x, t = threadIdx.x, i = b * 1024 + t;
    int v = (i < n) ? cnt[i] : 0;
    lds[t] = v;
    __syncthreads();
    for (int off = 1; off < 1024; off <<= 1) {
        int x = (t >= off) ? lds[t - off] : 0;
        __syncthreads();
        lds[t] += x;
        __syncthreads();
    }
    if (i < n) part[i] = lds[t] - v;
    if (t == 1023) bsum[b] = lds[t];
}

__global__ void scan2_k(const int* __restrict__ bsum, int* __restrict__ carry,
                        int nb, int* __restrict__ total) {
    if (threadIdx.x == 0) {
        int c = 0;
        for (int b = 0; b < nb; ++b) { carry[b] = c; c += bsum[b]; }
        total[0] = c;
    }
}

__global__ void scan3_k(const int* __restrict__ part, const int* __restrict__ carry,
                        const int* __restrict__ total, int* __restrict__ row_ptr, int n) {
    int i = blockIdx.x * 256 + threadIdx.x;
    if (i < n) row_ptr[i] = part[i] + carry[i >> 10];
    else if (i == n) row_ptr[n] = total[0];
}

__global__ void scatter_k(const int* __restrict__ src, const int* __restrict__ dst,
                          const int* __restrict__ row_ptr, int* __restrict__ cnt2,
                          int* __restrict__ csr_src, int E) {
    int e = blockIdx.x * 256 + threadIdx.x;
    if (e < E) {
        int d = dst[e];
        int pos = row_ptr[d] + atomicAdd(&cnt2[d], 1);
        csr_src[pos] = src[e];
    }
}

// ---------------- batched f32 -> bf16 convert ----------------
struct Cvt { const float* s[12]; bf16* d[12]; int n[12]; };

__global__ void cvt_many_k(Cvt c) {
    int a = blockIdx.y;
    int n4 = c.n[a] >> 2;
    const float4* s = (const float4*)c.s[a];
    uint2* d = (uint2*)c.d[a];
    for (int i = blockIdx.x * 256 + threadIdx.x; i < n4; i += gridDim.x * 256) {
        float4 v = s[i];
        d[i] = make_uint2(pk2(v.x, v.y), pk2(v.z, v.w));
    }
}

// ---------------- shared GEMM helpers ----------------
template<int MR, int NF, int NKS>
__device__ __forceinline__ void mm2(const char* A, int rbA, const char* W, int rbW,
                                    int wr, int wc, int lr, int lk, f4 (&acc)[MR][NF])
{
#pragma unroll
    for (int ks = 0; ks < NKS; ++ks) {
        int w = ks * 64 + (lk << 4);
        s8 af[MR], wf[NF];
#pragma unroll
        for (int m = 0; m < MR; ++m) {
            int ar = wr * (MR * 16) + m * 16 + lr;
            af[m] = *(const s8*)(A + ar * rbA + (w ^ ((ar & 7) << 4)));
        }
#pragma unroll
        for (int n = 0; n < NF; ++n) {
            int wrow = wc * (NF << 4) + n * 16 + lr;
            wf[n] = *(const s8*)(W + wrow * rbW + (w ^ ((wrow & 7) << 4)));
        }
#pragma unroll
        for (int m = 0; m < MR; ++m)
#pragma unroll
            for (int n = 0; n < NF; ++n)
                acc[m][n] = __builtin_amdgcn_mfma_f32_16x16x32_bf16(af[m], wf[n], acc[m][n], 0, 0, 0);
    }
}

// direct stage (load+swizzled LDS write), 512 thr
template<int R, int KK>
__device__ __forceinline__ void stage_w(char* dst, const bf16* __restrict__ W, int t) {
    constexpr int K8 = KK / 8;
    constexpr int SH = (K8 == 16) ? 4 : 5;
#pragma unroll 2
    for (int f = t; f < R * K8; f += 512) {
        int r = f >> SH, k8 = f & (K8 - 1);
        uint4 wv = *(const uint4*)&W[(size_t)r * KK + (k8 << 3)];
        *(uint4*)(dst + r * (KK * 2) + ((k8 << 4) ^ ((r & 7) << 4))) = wv;
    }
}

// split stage: issue linear global loads early (flat index == linear uint4 index),
// write swizzled to LDS later (after a barrier, under cover of intervening compute)
template<int NLD>
__device__ __forceinline__ void stage_load(uint4 (&buf)[NLD], const bf16* __restrict__ W, int t) {
#pragma unroll
    for (int j = 0; j < NLD; ++j) buf[j] = ((const uint4*)W)[t + j * 512];
}

template<int KK, int NLD>
__device__ __forceinline__ void stage_write(char* dst, const uint4 (&buf)[NLD], int t) {
    constexpr int K8 = KK / 8;
    constexpr int SH = (K8 == 16) ? 4 : 5;
#pragma unroll
    for (int j = 0; j < NLD; ++j) {
        int f = t + j * 512;
        int r = f >> SH, k8 = f & (K8 - 1);
        *(uint4*)(dst + r * (KK * 2) + ((k8 << 4) ^ ((r & 7) << 4))) = buf[j];
    }
}

// ---------------- bf16 MFMA GEMM, 64x128 tile (prologue / head) ----------------
__global__ __launch_bounds__(256, 2)
void gemm_k(const bf16* __restrict__ A, const bf16* __restrict__ A2,
            const bf16* __restrict__ W0, const bf16* __restrict__ W1, const bf16* __restrict__ W2,
            const float* __restrict__ b0, const float* __restrict__ b1, const float* __restrict__ b2,
            float* __restrict__ Cf0,
            bf16* __restrict__ Cb0, bf16* __restrict__ Cb1, bf16* __restrict__ Cb2,
            unsigned char* __restrict__ C81, unsigned char* __restrict__ C82,
            int N, int K, int M, int post)
{
    __shared__ unsigned short Al[64 * 128];
    __shared__ unsigned short Wl[128 * 128];
    int z = blockIdx.z;
    const bf16* W    = (z == 0) ? W0 : (z == 1 ? W1 : W2);
    const float* bia = (z == 0) ? b0 : (z == 1 ? b1 : b2);
    bf16*  Cb        = (z == 0) ? Cb0 : (z == 1 ? Cb1 : Cb2);
    float* Cf        = (z == 0) ? Cf0 : nullptr;
    unsigned char* C8 = (z == 1) ? C81 : (z == 2 ? C82 : nullptr);
    int n0 = blockIdx.x * 64, moff = blockIdx.y * 128;
    int t = threadIdx.x;
    int lane = t & 63, wid = t >> 6;
    int wr = wid >> 1, wc = wid & 1;
    int lr = lane & 15, lk = lane >> 4;

    f4 acc[2][4];
#pragma unroll
    for (int m = 0; m < 2; ++m)
#pragma unroll
        for (int n = 0; n < 4; ++n) acc[m][n] = (f4){0.f, 0.f, 0.f, 0.f};

    const char* Ac = (const char*)Al;
    const char* Wc = (const char*)Wl;

    for (int koff = 0; koff < K; koff += 128) {
        int chunk = (K - koff < 128) ? (K - koff) : 128;
        int ksh = (chunk == 64) ? 3 : 4;
        int k8s = 1 << ksh;
        int rowb = chunk * 2;
        for (int f = t; f < (64 << ksh); f += 256) {
            int r = f >> ksh, k8 = f & (k8s - 1);
            int row = n0 + r;
            uint4 av = make_uint4(0, 0, 0, 0);
            if (row < N) {
                av = *(const uint4*)&A[(size_t)row * K + koff + (k8 << 3)];
                if (A2) {
                    uint4 a2 = *(const uint4*)&A2[(size_t)row * K + koff + (k8 << 3)];
                    av.x = addpk(av.x, a2.x); av.y = addpk(av.y, a2.y);
                    av.z = addpk(av.z, a2.z); av.w = addpk(av.w, a2.w);
                }
            }
            *(uint4*)((char*)Al + r * rowb + ((k8 << 4) ^ ((r & 7) << 4))) = av;
        }
        for (int f = t; f < (128 << ksh); f += 256) {
            int r = f >> ksh, k8 = f & (k8s - 1);
            uint4 wv = *(const uint4*)&W[(size_t)(moff + r) * K + koff + (k8 << 3)];
            *(uint4*)((char*)Wl + r * rowb + ((k8 << 4) ^ ((r & 7) << 4))) = wv;
        }
        __syncthreads();
        int nks = chunk >> 5;
        for (int ks = 0; ks < nks; ++ks) {
            int w = ks * 64 + (lk << 4);
            s8 af[2], wf[4];
#pragma unroll
            for (int m = 0; m < 2; ++m) {
                int ar = wr * 32 + m * 16 + lr;
                af[m] = *(const s8*)(Ac + ar * rowb + (w ^ ((ar & 7) << 4)));
            }
#pragma unroll
            for (int n = 0; n < 4; ++n) {
                int wrow = wc * 64 + n * 16 + lr;
                wf[n] = *(const s8*)(Wc + wrow * rowb + (w ^ ((wrow & 7) << 4)));
            }
#pragma unroll
            for (int m = 0; m < 2; ++m)
#pragma unroll
                for (int n = 0; n < 4; ++n)
                    acc[m][n] = __builtin_amdgcn_mfma_f32_16x16x32_bf16(af[m], wf[n], acc[m][n], 0, 0, 0);
        }
        __syncthreads();
    }

    int gcol[4];
#pragma unroll
    for (int n = 0; n < 4; ++n) gcol[n] = moff + wc * 64 + n * 16 + lr;
    float bias_[4];
#pragma unroll
    for (int n = 0; n < 4; ++n) bias_[n] = bia ? bia[gcol[n]] : 0.f;
#pragma unroll
    for (int m = 0; m < 2; ++m)
#pragma unroll
        for (int i = 0; i < 4; ++i) {
            int row = n0 + wr * 32 + m * 16 + lk * 4 + i;
            if (row < N) {
#pragma unroll
                for (int n = 0; n < 4; ++n) {
                    float v = acc[m][n][i] + bias_[n];
                    if (post == 1) v = fmaxf(v, 0.f);
                    else if (post == 2) v = (v > 0.f) ? 1.0507009873554805f * v
                                                      : 1.7580993408473766f * expm1f(v);
                    if (Cf) Cf[(size_t)row * M + gcol[n]] = v;
                    if (Cb) Cb[(size_t)row * M + gcol[n]] = __float2bfloat16(v);
                    if (C8) C8[(size_t)row * M + gcol[n]] = f2fp8(v);
                }
            }
        }
}

// ---------------- mega-fused layer kernel: pipelined staging, 8 barriers ----------------
// 96 rows/block, 512 thr, 136 KB LDS, single block-round. Weight stages are split
// issue-early / write-late so L2 latency hides under the intervening MFMA phase.
// QKV tail merged: Wq+Wk in smW, Wv in smF, one compute phase for all three.
__global__ __launch_bounds__(512, 1)
void layer_k(const bf16* __restrict__ attn_b, const bf16* __restrict__ Iw,
             bf16* __restrict__ hres, float* __restrict__ hout_f,
             bf16* __restrict__ Qo, unsigned char* __restrict__ Ko,
             unsigned char* __restrict__ Vo, int doQKV,
             const bf16* __restrict__ Wo, const float* __restrict__ bo,
             const bf16* __restrict__ Wf1, const float* __restrict__ bf1,
             const bf16* __restrict__ Wf2, const float* __restrict__ bf2,
             const bf16* __restrict__ Wq, const float* __restrict__ bqv,
             const bf16* __restrict__ Wk, const float* __restrict__ bkv,
             const bf16* __restrict__ Wv, const float* __restrict__ bvv,
             const float* __restrict__ g1v, const float* __restrict__ b1v,
             const float* __restrict__ g2v, const float* __restrict__ b2v)
{
    extern __shared__ char sm[];
    char* smA = sm;                  // 24K  (96 rows x 256 B)
    char* smW = sm + 24576;          // 64K
    char* smF = sm + 90112;          // 48K  (96 rows x 512 B)
    float* redS1 = (float*)smF;      // LN1 stats: F dead until P4
    float* redQ1 = redS1 + 384;
    float* redS2 = (float*)smA;      // LN2 stats: A dead after GEMM2
    float* redQ2 = redS2 + 384;

    int n0 = blockIdx.x * ROWS;
    int t = threadIdx.x;
    int lane = t & 63, wid = t >> 6;
    int wr = wid >> 2, wc = wid & 3;             // 2 x 4 wave grid
    int lr = lane & 15, lk = lane >> 4;
    int gcol[2] = { wc * 32 + lr, wc * 32 + 16 + lr };
    int lrow[3][4];
#pragma unroll
    for (int m = 0; m < 3; ++m)
#pragma unroll
        for (int i = 0; i < 4; ++i) lrow[m][i] = wr * 48 + m * 16 + lk * 4 + i;

    uint4 pbuf[8];                                // in-flight weight stage buffer

    // ---- P1: stage A_in + Wo direct; ISSUE Wf1 loads ----
    for (int f = t; f < ROWS * 16; f += 512) {
        int r = f >> 4, k8 = f & 15;
        int row = n0 + r;
        uint4 av = make_uint4(0, 0, 0, 0);
        if (row < NN) {
            av = *(const uint4*)&attn_b[(size_t)row * DM + (k8 << 3)];
            uint4 a2 = *(const uint4*)&Iw[(size_t)row * DM + (k8 << 3)];
            av.x = addpk(av.x, a2.x); av.y = addpk(av.y, a2.y);
            av.z = addpk(av.z, a2.z); av.w = addpk(av.w, a2.w);
        }
        *(uint4*)(smA + r * 256 + ((k8 << 4) ^ ((r & 7) << 4))) = av;
    }
    stage_w<128, 128>(smW, Wo, t);
    stage_load<8>(pbuf, Wf1, t);                  // Wf1 in flight across P2
    __syncthreads();                                           // B1

    // ---- P2: GEMM1 + bo + h residual + LN1 stats ----
    f4 acc1[3][2];
#pragma unroll
    for (int m = 0; m < 3; ++m) { acc1[m][0] = (f4){0,0,0,0}; acc1[m][1] = (f4){0,0,0,0}; }
    mm2<3, 2, 4>(smA, 256, smW, 256, wr, wc, lr, lk, acc1);
    {
        float b_[2] = { bo[gcol[0]], bo[gcol[1]] };
#pragma unroll
        for (int m = 0; m < 3; ++m)
#pragma unroll
            for (int i = 0; i < 4; ++i) {
                int row = n0 + lrow[m][i];
                bool ok = row < NN;
#pragma unroll
                for (int n = 0; n < 2; ++n) {
                    float r = ok ? __bfloat162float(hres[(size_t)row * DM + gcol[n]]) : 0.f;
                    acc1[m][n][i] += b_[n] + r;
                }
            }
    }
#pragma unroll
    for (int m = 0; m < 3; ++m)
#pragma unroll
        for (int i = 0; i < 4; ++i) {
            float s = acc1[m][0][i] + acc1[m][1][i];
            float q = acc1[m][0][i] * acc1[m][0][i] + acc1[m][1][i] * acc1[m][1][i];
            s += __shfl_xor(s, 1); s += __shfl_xor(s, 2); s += __shfl_xor(s, 4); s += __shfl_xor(s, 8);
            q += __shfl_xor(q, 1); q += __shfl_xor(q, 2); q += __shfl_xor(q, 4); q += __shfl_xor(q, 8);
            if (lr == 0) { redS1[wc * ROWS + lrow[m][i]] = s; redQ1[wc * ROWS + lrow[m][i]] = q; }
        }
    __syncthreads();                                           // B2

    // ---- P3: LN1 finalize -> h2 to smA; WRITE Wf1; ISSUE Wf2 ----
    {
        float gam[2] = { g1v[gcol[0]], g1v[gcol[1]] };
        float bet[2] = { b1v[gcol[0]], b1v[gcol[1]] };
#pragma unroll
        for (int m = 0; m < 3; ++m)
#pragma unroll
            for (int i = 0; i < 4; ++i) {
                int lw = lrow[m][i];
                float s = redS1[lw] + redS1[ROWS + lw] + redS1[2 * ROWS + lw] + redS1[3 * ROWS + lw];
                float q = redQ1[lw] + redQ1[ROWS + lw] + redQ1[2 * ROWS + lw] + redQ1[3 * ROWS + lw];
                float mean = s * 0.0078125f;
                float var  = q * 0.0078125f - mean * mean;
                float rstd = rsqrtf(var + 1e-5f);
#pragma unroll
                for (int n = 0; n < 2; ++n)
                    acc1[m][n][i] = (acc1[m][n][i] - mean) * rstd * gam[n] + bet[n];
            }
    }
#pragma unroll
    for (int m = 0; m < 3; ++m)
#pragma unroll
        for (int i = 0; i < 4; ++i) {
            int rw = lrow[m][i];
#pragma unroll
            for (int n = 0; n < 2; ++n)
                *(unsigned short*)(smA + rw * 256 + ((gcol[n] * 2) ^ ((rw & 7) << 4))) = f2bu(acc1[m][n][i]);
        }
    stage_write<128, 8>(smW, pbuf, t);            // Wf1 -> smW (256x128)
    stage_load<8>(pbuf, Wf2, t);                  // Wf2 in flight across P4
    __syncthreads();                                           // B3

    // ---- P4: GEMM2: ffmid = relu(h2 @ Wf1^T + bf1), 96x256 -> smF ----
    {
        f4 acc2[3][4];
#pragma unroll
        for (int m = 0; m < 3; ++m)
#pragma unroll
            for (int n = 0; n < 4; ++n) acc2[m][n] = (f4){0,0,0,0};
        mm2<3, 4, 4>(smA, 256, smW, 256, wr, wc, lr, lk, acc2);
        int gc2[4];
        float b_[4];
#pragma unroll
        for (int n = 0; n < 4; ++n) { gc2[n] = wc * 64 + n * 16 + lr; b_[n] = bf1[gc2[n]]; }
#pragma unroll
        for (int m = 0; m < 3; ++m)
#pragma unroll
            for (int i = 0; i < 4; ++i) {
                int rw = lrow[m][i];
#pragma unroll
                for (int n = 0; n < 4; ++n) {
                    float v = fmaxf(acc2[m][n][i] + b_[n], 0.f);
                    *(unsigned short*)(smF + rw * 512 + ((gc2[n] * 2) ^ ((rw & 7) << 4))) = f2bu(v);
                }
            }
    }
    __syncthreads();                                           // B4

    // ---- P5: WRITE Wf2; ISSUE Wq+Wk ----
    stage_write<256, 8>(smW, pbuf, t);            // Wf2 -> smW (128x256)
    uint4 qkbuf[8];
    if (doQKV) {
        stage_load<4>(*(uint4(*)[4])&qkbuf[0], Wq, t);
        stage_load<4>(*(uint4(*)[4])&qkbuf[4], Wk, t);
    }
    __syncthreads();                                           // B5

    // ---- P6: GEMM3 (K=256) + bf2 + h2(reg) residual + LN2 stats ----
    f4 acc3[3][2];
#pragma unroll
    for (int m = 0; m < 3; ++m) { acc3[m][0] = (f4){0,0,0,0}; acc3[m][1] = (f4){0,0,0,0}; }
    mm2<3, 2, 8>(smF, 512, smW, 512, wr, wc, lr, lk, acc3);
    {
        float b_[2] = { bf2[gcol[0]], bf2[gcol[1]] };
#pragma unroll
        for (int m = 0; m < 3; ++m)
#pragma unroll
            for (int i = 0; i < 4; ++i)
#pragma unroll
                for (int n = 0; n < 2; ++n)
                    acc3[m][n][i] += b_[n] + acc1[m][n][i];
    }
#pragma unroll
    for (int m = 0; m < 3; ++m)
#pragma unroll
        for (int i = 0; i < 4; ++i) {
            float s = acc3[m][0][i] + acc3[m][1][i];
            float q = acc3[m][0][i] * acc3[m][0][i] + acc3[m][1][i] * acc3[m][1][i];
            s += __shfl_xor(s, 1); s += __shfl_xor(s, 2); s += __shfl_xor(s, 4); s += __shfl_xor(s, 8);
            q += __shfl_xor(q, 1); q += __shfl_xor(q, 2); q += __shfl_xor(q, 4); q += __shfl_xor(q, 8);
            if (lr == 0) { redS2[wc * ROWS + lrow[m][i]] = s; redQ2[wc * ROWS + lrow[m][i]] = q; }
        }
    __syncthreads();                                           // B6

    // ---- P7: LN2 finalize + h stores; WRITE Wq/Wk; ISSUE Wv ----
    {
        float gam[2] = { g2v[gcol[0]], g2v[gcol[1]] };
        float bet[2] = { b2v[gcol[0]], b2v[gcol[1]] };
#pragma unroll
        for (int m = 0; m < 3; ++m)
#pragma unroll
            for (int i = 0; i < 4; ++i) {
                int lw = lrow[m][i];
                float s = redS2[lw] + redS2[ROWS + lw] + redS2[2 * ROWS + lw] + redS2[3 * ROWS + lw];
                float q = redQ2[lw] + redQ2[ROWS + lw] + redQ2[2 * ROWS + lw] + redQ2[3 * ROWS + lw];
                float mean = s * 0.0078125f;
                float var  = q * 0.0078125f - mean * mean;
                float rstd = rsqrtf(var + 1e-5f);
                int row = n0 + lw;
#pragma unroll
                for (int n = 0; n < 2; ++n) {
                    float o = (acc3[m][n][i] - mean) * rstd * gam[n] + bet[n];
                    acc3[m][n][i] = o;
                    if (row < NN) {
                        hres[(size_t)row * DM + gcol[n]] = __float2bfloat16(o);
                        if (hout_f) hout_f[(size_t)row * DM + gcol[n]] = o;
                    }
                }
            }
    }
    if (!doQKV) return;
    stage_write<128, 4>(smW,         *(uint4(*)[4])&qkbuf[0], t);   // Wq -> smW[0:32K)
    stage_write<128, 4>(smW + 32768, *(uint4(*)[4])&qkbuf[4], t);   // Wk -> smW[32K:64K)
    stage_load<4>(*(uint4(*)[4])&pbuf[0], Wv, t);                   // Wv in flight
    __syncthreads();                                           // B7

    // ---- P8: h_new -> smA (stats dead); WRITE Wv -> smF ----
#pragma unroll
    for (int m = 0; m < 3; ++m)
#pragma unroll
        for (int i = 0; i < 4; ++i) {
            int rw = lrow[m][i];
#pragma unroll
            for (int n = 0; n < 2; ++n)
                *(unsigned short*)(smA + rw * 256 + ((gcol[n] * 2) ^ ((rw & 7) << 4))) = f2bu(acc3[m][n][i]);
        }
    stage_write<128, 4>(smF, *(uint4(*)[4])&pbuf[0], t);
    __syncthreads();                                           // B8

    // ---- P9: GEMM_Q + GEMM_K + GEMM_V (one phase, no more barriers) ----
    {
        f4 aq[3][2];
#pragma unroll
        for (int m = 0; m < 3; ++m) { aq[m][0] = (f4){0,0,0,0}; aq[m][1] = (f4){0,0,0,0}; }
        mm2<3, 2, 4>(smA, 256, smW, 256, wr, wc, lr, lk, aq);
        float b_[2] = { bqv[gcol[0]], bqv[gcol[1]] };
#pragma unroll
        for (int m = 0; m < 3; ++m)
#pragma unroll
            for (int i = 0; i < 4; ++i) {
                int row = n0 + lrow[m][i];
                if (row < NN)
#pragma unroll
                    for (int n = 0; n < 2; ++n)
                        Qo[(size_t)row * DM + gcol[n]] = __float2bfloat16(aq[m][n][i] + b_[n]);
            }
    }
    {
        f4 ak[3][2];
#pragma unroll
        for (int m = 0; m < 3; ++m) { ak[m][0] = (f4){0,0,0,0}; ak[m][1] = (f4){0,0,0,0}; }
        mm2<3, 2, 4>(smA, 256, smW + 32768, 256, wr, wc, lr, lk, ak);
        float b_[2] = { bkv[gcol[0]], bkv[gcol[1]] };
#pragma unroll
        for (int m = 0; m < 3; ++m)
#pragma unroll
            for (int i = 0; i < 4; ++i) {
                int row = n0 + lrow[m][i];
                if (row < NN)
#pragma unroll
                    for (int n = 0; n < 2; ++n)
                        Ko[(size_t)row * DM + gcol[n]] = f2fp8(ak[m][n][i] + b_[n]);
            }
    }
    {
        f4 av_[3][2];
#pragma unroll
        for (int m = 0; m < 3; ++m) { av_[m][0] = (f4){0,0,0,0}; av_[m][1] = (f4){0,0,0,0}; }
        mm2<3, 2, 4>(smA, 256, smF, 256, wr, wc, lr, lk, av_);
        float b_[2] = { bvv[gcol[0]], bvv[gcol[1]] };
#pragma unroll
        for (int m = 0; m < 3; ++m)
#pragma unroll
            for (int i = 0; i < 4; ++i) {
                int row = n0 + lrow[m][i];
                if (row < NN)
#pragma unroll
                    for (int n = 0; n < 2; ++n)
                        Vo[(size_t)row * DM + gcol[n]] = f2fp8(av_[m][n][i] + b_[n]);
            }
    }
}

// ---------------- edge attention: fp8 K/V, 8 lanes per edge (one head per lane) ----------------
__global__ __launch_bounds__(256)
void attn_k(const bf16* __restrict__ Q, const unsigned char* __restrict__ K8,
            const unsigned char* __restrict__ V8, const int* __restrict__ row_ptr,
            const int* __restrict__ csr, bf16* __restrict__ out)
{
    int lane = threadIdx.x & 63;
    int n = blockIdx.x * 4 + (threadIdx.x >> 6);
    int g = lane >> 3, sub = lane & 7;
    const uint4* K4 = (const uint4*)K8;
    const uint4* V4 = (const uint4*)V8;
    float q[16];
    {
        const uint4* Q4 = (const uint4*)Q;
        uint4 qa = Q4[n * 16 + sub * 2];
        uint4 qb = Q4[n * 16 + sub * 2 + 1];
        up8(qa, q); up8(qb, q + 8);
    }
    int e0 = row_ptr[n], e1 = row_ptr[n + 1];
    float acc[16];
#pragma unroll
    for (int j = 0; j < 16; ++j) acc[j] = 0.f;
    float zacc = 0.f;

    int sA = (e0 + g < e1) ? csr[e0 + g] : 0;
    uint4 k0 = K4[(size_t)sA * 8 + sub];
    uint4 v0 = V4[(size_t)sA * 8 + sub];
    int sB = (e0 + 8 + g < e1) ? csr[e0 + 8 + g] : 0;
    uint4 k1 = K4[(size_t)sB * 8 + sub];
    uint4 v1 = V4[(size_t)sB * 8 + sub];
    for (int base = e0; base < e1; base += 8) {
        int en = base + 16 + g;
        int s2 = (en < e1) ? csr[en] : 0;
        uint4 k2 = K4[(size_t)s2 * 8 + sub];      // 2-deep prefetch
        uint4 v2 = V4[(size_t)s2 * 8 + sub];
        float kf[16];
        fp8x4(k0.x, kf); fp8x4(k0.y, kf + 4); fp8x4(k0.z, kf + 8); fp8x4(k0.w, kf + 12);
        float p = 0.f;
#pragma unroll
        for (int j = 0; j < 16; ++j) p = fmaf(q[j], kf[j], p);
        float sc = __expf(fminf(fmaxf(p * 0.25f, -10.f), 10.f)) * 0.5f;
        if (base + g >= e1) sc = 0.f;
        float vf[16];
        fp8x4(v0.x, vf); fp8x4(v0.y, vf + 4); fp8x4(v0.z, vf + 8); fp8x4(v0.w, vf + 12);
#pragma unroll
        for (int j = 0; j < 16; ++j) acc[j] = fmaf(sc, vf[j], acc[j]);
        zacc += sc;
        k0 = k1; v0 = v1; k1 = k2; v1 = v2;
    }
#pragma unroll
    for (int j = 0; j < 16; ++j) {
        acc[j] += __shfl_xor(acc[j], 8);
        acc[j] += __shfl_xor(acc[j], 16);
        acc[j] += __shfl_xor(acc[j], 32);
    }
    zacc += __shfl_xor(zacc, 8);
    zacc += __shfl_xor(zacc, 16);
    zacc += __shfl_xor(zacc, 32);
    float inv = 1.f / (zacc + 1e-6f);
    if (g == 0) {
        uint4 o1, o2;
        o1.x = pk2(acc[0] * inv, acc[1] * inv);
        o1.y = pk2(acc[2] * inv, acc[3] * inv);
        o1.z = pk2(acc[4] * inv, acc[5] * inv);
        o1.w = pk2(acc[6] * inv, acc[7] * inv);
        o2.x = pk2(acc[8] * inv, acc[9] * inv);
        o2.y = pk2(acc[10] * inv, acc[11] * inv);
        o2.z = pk2(acc[12] * inv, acc[13] * inv);
        o2.w = pk2(acc[14] * inv, acc[15] * inv);
        ((uint4*)out)[n * 16 + sub * 2] = o1;
        ((uint4*)out)[n * 16 + sub * 2 + 1] = o2;
    }
}

// ---------------- host side ----------------
static inline void g1(hipStream_t st, const bf16* A, const bf16* A2, const bf16* W,
                      const float* bia, float* Cf, bf16* Cb, int N, int K, int M, int post)
{
    dim3 grid((N + 63) / 64, M / 128, 1);
    gemm_k<<<grid, 256, 0, st>>>(A, A2, W, nullptr, nullptr, bia, nullptr, nullptr,
                                 Cf, Cb, nullptr, nullptr, nullptr, nullptr, N, K, M, post);
}

static inline void g3(hipStream_t st, const bf16* A,
                      const bf16* W0, const float* b0, bf16* C0,
                      const bf16* W1, const float* b1, unsigned char* C1,
                      const bf16* W2, const float* b2, unsigned char* C2,
                      int N, int K, int M)
{
    dim3 grid((N + 63) / 64, M / 128, 3);
    gemm_k<<<grid, 256, 0, st>>>(A, nullptr, W0, W1, W2, b0, b1, b2,
                                 nullptr, C0, nullptr, nullptr, C1, C2, N, K, M, 0);
}

extern "C" void kernel_launch(void* const* d_in, const int* in_sizes, int n_in,
                              void* d_out, int out_size, void* d_ws, size_t ws_size,
                              hipStream_t stream)
{
    const float* x    = (const float*)d_in[0];
    const float* Iin  = (const float*)d_in[1];
    const int*   src  = (const int*)d_in[2];
    const int*   dst  = (const int*)d_in[3];
    const float* Wemb = (const float*)d_in[4];
    const float* Wq   = (const float*)d_in[5];  const float* bq  = (const float*)d_in[6];
    const float* Wk   = (const float*)d_in[7];  const float* bk  = (const float*)d_in[8];
    const float* Wv   = (const float*)d_in[9];  const float* bv  = (const float*)d_in[10];
    const float* Wi   = (const float*)d_in[11]; const float* bi  = (const float*)d_in[12];
    const float* Wo   = (const float*)d_in[13]; const float* bo  = (const float*)d_in[14];
    const float* g1g  = (const float*)d_in[15]; const float* be1 = (const float*)d_in[16];
    const float* g2g  = (const float*)d_in[17]; const float* be2 = (const float*)d_in[18];
    const float* Wf1  = (const float*)d_in[19]; const float* bf1 = (const float*)d_in[20];
    const float* Wf2  = (const float*)d_in[21]; const float* bf2 = (const float*)d_in[22];
    const float* Wm1  = (const float*)d_in[23]; const float* bm1 = (const float*)d_in[24];
    const float* Wm2  = (const float*)d_in[25]; const float* bm2 = (const float*)d_in[26];

    const size_t NF = (size_t)NN * DM;          // 2,560,000
    bf16* B      = (bf16*)d_ws;
    bf16* h_b    = B;                           // bf16 residual stream (in-place updated)
    bf16* Qb     = B + NF;
    unsigned char* K8 = (unsigned char*)(B + 2 * NF);   // N x 128 fp8
    unsigned char* V8 = (unsigned char*)(B + 3 * NF);
    bf16* attn_b = B + 4 * NF;
    bf16* Iw_b   = B + 5 * NF;
    bf16* wts    = B + 6 * NF;
    bf16* Wemb_b = wts;                 // 32768
    bf16* Wq_b   = wts + 32768;         // 16384
    bf16* Wk_b   = Wq_b + 16384;
    bf16* Wv_b   = Wk_b + 16384;
    bf16* Wo_b   = Wv_b + 16384;
    bf16* Wi_b   = Wo_b + 16384;        // 8192
    bf16* Wf1_b  = Wi_b + 8192;         // 32768
    bf16* Wf2_b  = Wf1_b + 32768;       // 32768
    bf16* Wm1_b  = Wf2_b + 32768;       // 16384
    bf16* Wm2_b  = Wm1_b + 16384;       // 32768
    bf16* wend   = Wm2_b + 32768;
    bf16* x_b    = Qb;                  // N x 256 (spans Qb + K8 slots), dead after embed
    bf16* Iin_b  = B + 3 * NF;          // N x 64 in V8 slot, dead before QKV0
    bf16* tmp_b  = Qb;                  // head mid (N x 128), Qb dead after last attn
    int* ib      = (int*)wend;
    int* cnt     = ib;
    int* cnt2    = ib + NN;
    int* row_ptr = ib + 2 * NN;
    int* csr     = ib + 3 * NN + 1;
    int* part    = csr + NE;
    int* bsum    = part + NN;
    int* carry   = bsum + 32;
    int* total   = carry + 32;

    // ---- CSR build (once per call) ----
    hipMemsetAsync(cnt,  0, NN * sizeof(int), stream);
    hipMemsetAsync(cnt2, 0, NN * sizeof(int), stream);
    hist_k<<<(NE + 255) / 256, 256, 0, stream>>>(dst, cnt, NE);
    const int nsb = (NN + 1023) / 1024;
    scan1_k<<<nsb, 1024, 0, stream>>>(cnt, part, bsum, NN);
    scan2_k<<<1, 64, 0, stream>>>(bsum, carry, nsb, total);
    scan3_k<<<(NN + 256) / 256, 256, 0, stream>>>(part, carry, total, row_ptr, NN);
    scatter_k<<<(NE + 255) / 256, 256, 0, stream>>>(src, dst, row_ptr, cnt2, csr, NE);

    // ---- batched f32->bf16 conversion of x, I, and all weights ----
    Cvt c;
    c.s[0] = x;    c.d[0] = x_b;    c.n[0] = NN * DIN;
    c.s[1] = Iin;  c.d[1] = Iin_b;  c.n[1] = NN * 64;
    c.s[2] = Wemb; c.d[2] = Wemb_b; c.n[2] = 32768;
    c.s[3] = Wq;   c.d[3] = Wq_b;   c.n[3] = 16384;
    c.s[4] = Wk;   c.d[4] = Wk_b;   c.n[4] = 16384;
    c.s[5] = Wv;   c.d[5] = Wv_b;   c.n[5] = 16384;
    c.s[6] = Wo;   c.d[6] = Wo_b;   c.n[6] = 16384;
    c.s[7] = Wi;   c.d[7] = Wi_b;   c.n[7] = 8192;
    c.s[8] = Wf1;  c.d[8] = Wf1_b;  c.n[8] = 32768;
    c.s[9] = Wf2;  c.d[9] = Wf2_b;  c.n[9] = 32768;
    c.s[10] = Wm1; c.d[10] = Wm1_b; c.n[10] = 16384;
    c.s[11] = Wm2; c.d[11] = Wm2_b; c.n[11] = 32768;
    cvt_many_k<<<dim3(640, 12), 256, 0, stream>>>(c);

    // ---- prologue: embed, Iw, first-layer QKV (K/V straight to fp8) ----
    g1(stream, x_b,   nullptr, Wemb_b, nullptr, nullptr, h_b, NN, DIN, DM, 0);
    g1(stream, Iin_b, nullptr, Wi_b, bi, nullptr, Iw_b, NN, 64, DM, 0);
    g3(stream, h_b, Wq_b, bq, Qb, Wk_b, bk, K8, Wv_b, bv, V8, NN, DM, DM);

    // ---- 10 shared-weight layers: attn + mega-fused ----
    const int nblk = (NN + ROWS - 1) / ROWS;    // 209 <= 256 -> single round
    for (int l = 0; l < 10; ++l) {
        attn_k<<<NN / 4, 256, 0, stream>>>(Qb, K8, V8, row_ptr, csr, attn_b);
        layer_k<<<nblk, 512, 139264, stream>>>(
            attn_b, Iw_b, h_b, (l == 9) ? (float*)d_out : nullptr,
            Qb, K8, V8, (l < 9) ? 1 : 0,
            Wo_b, bo, Wf1_b, bf1, Wf2_b, bf2,
            Wq_b, bq, Wk_b, bk, Wv_b, bv,
            g1g, be1, g2g, be2);
    }

    // ---- reconstruction head ----
    g1(stream, h_b, nullptr, Wm1_b, bm1, nullptr, tmp_b, NN, DM, DM, 2);   // selu
    float* xhat = (float*)d_out + NF;
    g1(stream, tmp_b, nullptr, Wm2_b, bm2, xhat, nullptr, NN, DM, DIN, 0);
}

// Round 13
// 784.986 us; speedup vs baseline: 1.0041x; 1.0041x over previous
//
#include <hip/hip_runtime.h>
#include <hip/hip_bf16.h>

#define NN 20000      // nodes
#define NE 640000     // edges
#define DIN 256
#define DM  128
#define ROWS 96       // rows per layer_k block (209 blocks -> single scheduling round)

typedef __hip_bfloat16 bf16;
typedef __attribute__((ext_vector_type(8))) short s8;     // 8 bf16 (4 VGPRs) MFMA frag
typedef __attribute__((ext_vector_type(4))) float f4;     // 4 f32 acc
typedef __attribute__((ext_vector_type(2))) float fl2;

__device__ __forceinline__ float bu2f_lo(unsigned u) { union {unsigned u; float f;} c; c.u = u << 16; return c.f; }
__device__ __forceinline__ float bu2f_hi(unsigned u) { union {unsigned u; float f;} c; c.u = u & 0xffff0000u; return c.f; }
__device__ __forceinline__ unsigned short f2bu(float f) { bf16 t = __float2bfloat16(f); return *reinterpret_cast<unsigned short*>(&t); }
__device__ __forceinline__ unsigned pk2(float lo, float hi) { return (unsigned)f2bu(lo) | ((unsigned)f2bu(hi) << 16); }
__device__ __forceinline__ unsigned addpk(unsigned a, unsigned b) {
    return pk2(bu2f_lo(a) + bu2f_lo(b), bu2f_hi(a) + bu2f_hi(b));
}
__device__ __forceinline__ void up8(uint4 u, float* f) {
    f[0] = bu2f_lo(u.x); f[1] = bu2f_hi(u.x);
    f[2] = bu2f_lo(u.y); f[3] = bu2f_hi(u.y);
    f[4] = bu2f_lo(u.z); f[5] = bu2f_hi(u.z);
    f[6] = bu2f_lo(u.w); f[7] = bu2f_hi(u.w);
}

// ---------------- fp8 e4m3 (OCP) helpers: HW cvt if available, exact bit fallback ----
#if defined(__has_builtin)
#if __has_builtin(__builtin_amdgcn_cvt_pk_f32_fp8) && __has_builtin(__builtin_amdgcn_cvt_pk_fp8_f32)
#define HW_FP8 1
#endif
#endif

__device__ __forceinline__ void fp8x4(unsigned u, float* o) {
#ifdef HW_FP8
    fl2 lo = __builtin_amdgcn_cvt_pk_f32_fp8((int)u, false);
    fl2 hi = __builtin_amdgcn_cvt_pk_f32_fp8((int)u, true);
    o[0] = lo[0]; o[1] = lo[1]; o[2] = hi[0]; o[3] = hi[1];
#else
#pragma unroll
    for (int i = 0; i < 4; ++i) {
        unsigned b = (u >> (8 * i)) & 0xffu;
        unsigned w = ((b & 0x80u) << 24) | ((b & 0x7fu) << 20);
        o[i] = __uint_as_float(w) * 1.3292279957849159e36f;   // x2^120
    }
#endif
}

__device__ __forceinline__ unsigned char f2fp8(float v) {
#ifdef HW_FP8
    int r = __builtin_amdgcn_cvt_pk_fp8_f32(v, 0.f, 0, false);
    return (unsigned char)(r & 0xff);
#else
    float a = fabsf(v);
    unsigned s = (__float_as_uint(v) >> 24) & 0x80u;
    a = fminf(a, 448.f);
    unsigned out;
    if (a < 0.0009765625f) {
        out = 0;
    } else if (a < 0.015625f) {
        int q = (int)(a * 512.f + 0.5f);
        out = (unsigned)q;
    } else {
        unsigned bits = __float_as_uint(a);
        int e = (int)((bits >> 23) & 0xff) - 127;
        unsigned m = bits & 0x7fffffu;
        unsigned mr = m + 0x7ffffu + ((m >> 20) & 1u);
        if (mr >> 23) { mr = 0; e += 1; } else mr >>= 20;
        if (e > 8) { e = 8; mr = 7; }
        out = ((unsigned)(e + 7) << 3) | (mr & 7u);
    }
    return (unsigned char)(out | s);
#endif
}

// ---------------- CSR build (dst-sorted edge list) ----------------
__global__ void hist_k(const int* __restrict__ dst, int* __restrict__ cnt, int E) {
    int e = blockIdx.x * 256 + threadIdx.x;
    if (e < E) atomicAdd(&cnt[dst[e]], 1);
}

__global__ void scan1_k(const int* __restrict__ cnt, int* __restrict__ part,
                        int* __restrict__ bsum, int n) {
    __shared__ int lds[1024];
    int b = blockIdx.x, t = threadIdx.x, i = b * 1024 + t;
    int v = (i < n) ? cnt[i] : 0;
    lds[t] = v;
    __syncthreads();
    for (int off = 1; off < 1024; off <<= 1) {
        int x = (t >= off) ? lds[t - off] : 0;
        __syncthreads();
        lds[t] += x;
        __syncthreads();
    }
    if (i < n) part[i] = lds[t] - v;
    if (t == 1023) bsum[b] = lds[t];
}

__global__ void scan2_k(const int* __restrict__ bsum, int* __restrict__ carry,
                        int nb, int* __restrict__ total) {
    if (threadIdx.x == 0) {
        int c = 0;
        for (int b = 0; b < nb; ++b) { carry[b] = c; c += bsum[b]; }
        total[0] = c;
    }
}

__global__ void scan3_k(const int* __restrict__ part, const int* __restrict__ carry,
                        const int* __restrict__ total, int* __restrict__ row_ptr, int n) {
    int i = blockIdx.x * 256 + threadIdx.x;
    if (i < n) row_ptr[i] = part[i] + carry[i >> 10];
    else if (i == n) row_ptr[n] = total[0];
}

__global__ void scatter_k(const int* __restrict__ src, const int* __restrict__ dst,
                          const int* __restrict__ row_ptr, int* __restrict__ cnt2,
                          int* __restrict__ csr_src, int E) {
    int e = blockIdx.x * 256 + threadIdx.x;
    if (e < E) {
        int d = dst[e];
        int pos = row_ptr[d] + atomicAdd(&cnt2[d], 1);
        csr_src[pos] = src[e];
    }
}

// ---------------- batched f32 -> bf16 convert ----------------
struct Cvt { const float* s[12]; bf16* d[12]; int n[12]; };

__global__ void cvt_many_k(Cvt c) {
    int a = blockIdx.y;
    int n4 = c.n[a] >> 2;
    const float4* s = (const float4*)c.s[a];
    uint2* d = (uint2*)c.d[a];
    for (int i = blockIdx.x * 256 + threadIdx.x; i < n4; i += gridDim.x * 256) {
        float4 v = s[i];
        d[i] = make_uint2(pk2(v.x, v.y), pk2(v.z, v.w));
    }
}

// ---------------- shared GEMM helpers ----------------
template<int MR, int NF, int NKS>
__device__ __forceinline__ void mm2(const char* A, int rbA, const char* W, int rbW,
                                    int wr, int wc, int lr, int lk, f4 (&acc)[MR][NF])
{
#pragma unroll
    for (int ks = 0; ks < NKS; ++ks) {
        int w = ks * 64 + (lk << 4);
        s8 af[MR], wf[NF];
#pragma unroll
        for (int m = 0; m < MR; ++m) {
            int ar = wr * (MR * 16) + m * 16 + lr;
            af[m] = *(const s8*)(A + ar * rbA + (w ^ ((ar & 7) << 4)));
        }
#pragma unroll
        for (int n = 0; n < NF; ++n) {
            int wrow = wc * (NF << 4) + n * 16 + lr;
            wf[n] = *(const s8*)(W + wrow * rbW + (w ^ ((wrow & 7) << 4)));
        }
#pragma unroll
        for (int m = 0; m < MR; ++m)
#pragma unroll
            for (int n = 0; n < NF; ++n)
                acc[m][n] = __builtin_amdgcn_mfma_f32_16x16x32_bf16(af[m], wf[n], acc[m][n], 0, 0, 0);
    }
}

// direct stage (load+swizzled LDS write), 512 thr
template<int R, int KK>
__device__ __forceinline__ void stage_w(char* dst, const bf16* __restrict__ W, int t) {
    constexpr int K8 = KK / 8;
    constexpr int SH = (K8 == 16) ? 4 : 5;
#pragma unroll 2
    for (int f = t; f < R * K8; f += 512) {
        int r = f >> SH, k8 = f & (K8 - 1);
        uint4 wv = *(const uint4*)&W[(size_t)r * KK + (k8 << 3)];
        *(uint4*)(dst + r * (KK * 2) + ((k8 << 4) ^ ((r & 7) << 4))) = wv;
    }
}

// split stage: issue linear global loads early (flat index == linear uint4 index),
// write swizzled to LDS later (after a barrier, under cover of intervening compute)
template<int NLD>
__device__ __forceinline__ void stage_load(uint4 (&buf)[NLD], const bf16* __restrict__ W, int t) {
#pragma unroll
    for (int j = 0; j < NLD; ++j) buf[j] = ((const uint4*)W)[t + j * 512];
}

template<int KK, int NLD>
__device__ __forceinline__ void stage_write(char* dst, const uint4 (&buf)[NLD], int t) {
    constexpr int K8 = KK / 8;
    constexpr int SH = (K8 == 16) ? 4 : 5;
#pragma unroll
    for (int j = 0; j < NLD; ++j) {
        int f = t + j * 512;
        int r = f >> SH, k8 = f & (K8 - 1);
        *(uint4*)(dst + r * (KK * 2) + ((k8 << 4) ^ ((r & 7) << 4))) = buf[j];
    }
}

// ---------------- bf16 MFMA GEMM, 64x128 tile (prologue / head) ----------------
__global__ __launch_bounds__(256, 2)
void gemm_k(const bf16* __restrict__ A, const bf16* __restrict__ A2,
            const bf16* __restrict__ W0, const bf16* __restrict__ W1, const bf16* __restrict__ W2,
            const float* __restrict__ b0, const float* __restrict__ b1, const float* __restrict__ b2,
            float* __restrict__ Cf0,
            bf16* __restrict__ Cb0, bf16* __restrict__ Cb1, bf16* __restrict__ Cb2,
            unsigned char* __restrict__ C81, unsigned char* __restrict__ C82,
            int N, int K, int M, int post)
{
    __shared__ unsigned short Al[64 * 128];
    __shared__ unsigned short Wl[128 * 128];
    int z = blockIdx.z;
    const bf16* W    = (z == 0) ? W0 : (z == 1 ? W1 : W2);
    const float* bia = (z == 0) ? b0 : (z == 1 ? b1 : b2);
    bf16*  Cb        = (z == 0) ? Cb0 : (z == 1 ? Cb1 : Cb2);
    float* Cf        = (z == 0) ? Cf0 : nullptr;
    unsigned char* C8 = (z == 1) ? C81 : (z == 2 ? C82 : nullptr);
    int n0 = blockIdx.x * 64, moff = blockIdx.y * 128;
    int t = threadIdx.x;
    int lane = t & 63, wid = t >> 6;
    int wr = wid >> 1, wc = wid & 1;
    int lr = lane & 15, lk = lane >> 4;

    f4 acc[2][4];
#pragma unroll
    for (int m = 0; m < 2; ++m)
#pragma unroll
        for (int n = 0; n < 4; ++n) acc[m][n] = (f4){0.f, 0.f, 0.f, 0.f};

    const char* Ac = (const char*)Al;
    const char* Wc = (const char*)Wl;

    for (int koff = 0; koff < K; koff += 128) {
        int chunk = (K - koff < 128) ? (K - koff) : 128;
        int ksh = (chunk == 64) ? 3 : 4;
        int k8s = 1 << ksh;
        int rowb = chunk * 2;
        for (int f = t; f < (64 << ksh); f += 256) {
            int r = f >> ksh, k8 = f & (k8s - 1);
            int row = n0 + r;
            uint4 av = make_uint4(0, 0, 0, 0);
            if (row < N) {
                av = *(const uint4*)&A[(size_t)row * K + koff + (k8 << 3)];
                if (A2) {
                    uint4 a2 = *(const uint4*)&A2[(size_t)row * K + koff + (k8 << 3)];
                    av.x = addpk(av.x, a2.x); av.y = addpk(av.y, a2.y);
                    av.z = addpk(av.z, a2.z); av.w = addpk(av.w, a2.w);
                }
            }
            *(uint4*)((char*)Al + r * rowb + ((k8 << 4) ^ ((r & 7) << 4))) = av;
        }
        for (int f = t; f < (128 << ksh); f += 256) {
            int r = f >> ksh, k8 = f & (k8s - 1);
            uint4 wv = *(const uint4*)&W[(size_t)(moff + r) * K + koff + (k8 << 3)];
            *(uint4*)((char*)Wl + r * rowb + ((k8 << 4) ^ ((r & 7) << 4))) = wv;
        }
        __syncthreads();
        int nks = chunk >> 5;
        for (int ks = 0; ks < nks; ++ks) {
            int w = ks * 64 + (lk << 4);
            s8 af[2], wf[4];
#pragma unroll
            for (int m = 0; m < 2; ++m) {
                int ar = wr * 32 + m * 16 + lr;
                af[m] = *(const s8*)(Ac + ar * rowb + (w ^ ((ar & 7) << 4)));
            }
#pragma unroll
            for (int n = 0; n < 4; ++n) {
                int wrow = wc * 64 + n * 16 + lr;
                wf[n] = *(const s8*)(Wc + wrow * rowb + (w ^ ((wrow & 7) << 4)));
            }
#pragma unroll
            for (int m = 0; m < 2; ++m)
#pragma unroll
                for (int n = 0; n < 4; ++n)
                    acc[m][n] = __builtin_amdgcn_mfma_f32_16x16x32_bf16(af[m], wf[n], acc[m][n], 0, 0, 0);
        }
        __syncthreads();
    }

    int gcol[4];
#pragma unroll
    for (int n = 0; n < 4; ++n) gcol[n] = moff + wc * 64 + n * 16 + lr;
    float bias_[4];
#pragma unroll
    for (int n = 0; n < 4; ++n) bias_[n] = bia ? bia[gcol[n]] : 0.f;
#pragma unroll
    for (int m = 0; m < 2; ++m)
#pragma unroll
        for (int i = 0; i < 4; ++i) {
            int row = n0 + wr * 32 + m * 16 + lk * 4 + i;
            if (row < N) {
#pragma unroll
                for (int n = 0; n < 4; ++n) {
                    float v = acc[m][n][i] + bias_[n];
                    if (post == 1) v = fmaxf(v, 0.f);
                    else if (post == 2) v = (v > 0.f) ? 1.0507009873554805f * v
                                                      : 1.7580993408473766f * expm1f(v);
                    if (Cf) Cf[(size_t)row * M + gcol[n]] = v;
                    if (Cb) Cb[(size_t)row * M + gcol[n]] = __float2bfloat16(v);
                    if (C8) C8[(size_t)row * M + gcol[n]] = f2fp8(v);
                }
            }
        }
}

// ---------------- mega-fused layer kernel: pipelined staging, 8 barriers ----------------
// 96 rows/block, 512 thr, 136 KB LDS, single block-round. Weight stages split
// issue-early / write-late so L2 latency hides under the intervening MFMA phase.
// amdgpu_waves_per_eu(2,2): LDS caps us at 1 block/CU = 2 waves/SIMD anyway, so tell
// the allocator -> VGPR budget 256, prefetch buffers stay in registers (R12 spilled
// at the heuristic 128 cap: WRITE_SIZE 20.8->56.6 MB).
__global__ __launch_bounds__(512) __attribute__((amdgpu_waves_per_eu(2, 2)))
void layer_k(const bf16* __restrict__ attn_b, const bf16* __restrict__ Iw,
             bf16* __restrict__ hres, float* __restrict__ hout_f,
             bf16* __restrict__ Qo, unsigned char* __restrict__ Ko,
             unsigned char* __restrict__ Vo, int doQKV,
             const bf16* __restrict__ Wo, const float* __restrict__ bo,
             const bf16* __restrict__ Wf1, const float* __restrict__ bf1,
             const bf16* __restrict__ Wf2, const float* __restrict__ bf2,
             const bf16* __restrict__ Wq, const float* __restrict__ bqv,
             const bf16* __restrict__ Wk, const float* __restrict__ bkv,
             const bf16* __restrict__ Wv, const float* __restrict__ bvv,
             const float* __restrict__ g1v, const float* __restrict__ b1v,
             const float* __restrict__ g2v, const float* __restrict__ b2v)
{
    extern __shared__ char sm[];
    char* smA = sm;                  // 24K  (96 rows x 256 B)
    char* smW = sm + 24576;          // 64K
    char* smF = sm + 90112;          // 48K  (96 rows x 512 B)
    float* redS1 = (float*)smF;      // LN1 stats: F dead until P4
    float* redQ1 = redS1 + 384;
    float* redS2 = (float*)smA;      // LN2 stats: A dead after GEMM2
    float* redQ2 = redS2 + 384;

    int n0 = blockIdx.x * ROWS;
    int t = threadIdx.x;
    int lane = t & 63, wid = t >> 6;
    int wr = wid >> 2, wc = wid & 3;             // 2 x 4 wave grid
    int lr = lane & 15, lk = lane >> 4;
    int gcol[2] = { wc * 32 + lr, wc * 32 + 16 + lr };
    int lrow[3][4];
#pragma unroll
    for (int m = 0; m < 3; ++m)
#pragma unroll
        for (int i = 0; i < 4; ++i) lrow[m][i] = wr * 48 + m * 16 + lk * 4 + i;

    uint4 pbuf[8];                                // in-flight weight stage buffer

    // ---- P1: stage A_in + Wo direct; ISSUE Wf1 loads ----
    for (int f = t; f < ROWS * 16; f += 512) {
        int r = f >> 4, k8 = f & 15;
        int row = n0 + r;
        uint4 av = make_uint4(0, 0, 0, 0);
        if (row < NN) {
            av = *(const uint4*)&attn_b[(size_t)row * DM + (k8 << 3)];
            uint4 a2 = *(const uint4*)&Iw[(size_t)row * DM + (k8 << 3)];
            av.x = addpk(av.x, a2.x); av.y = addpk(av.y, a2.y);
            av.z = addpk(av.z, a2.z); av.w = addpk(av.w, a2.w);
        }
        *(uint4*)(smA + r * 256 + ((k8 << 4) ^ ((r & 7) << 4))) = av;
    }
    stage_w<128, 128>(smW, Wo, t);
    stage_load<8>(pbuf, Wf1, t);                  // Wf1 in flight across P2
    __syncthreads();                                           // B1

    // ---- P2: GEMM1 + bo + h residual + LN1 stats ----
    f4 acc1[3][2];
#pragma unroll
    for (int m = 0; m < 3; ++m) { acc1[m][0] = (f4){0,0,0,0}; acc1[m][1] = (f4){0,0,0,0}; }
    mm2<3, 2, 4>(smA, 256, smW, 256, wr, wc, lr, lk, acc1);
    {
        float b_[2] = { bo[gcol[0]], bo[gcol[1]] };
#pragma unroll
        for (int m = 0; m < 3; ++m)
#pragma unroll
            for (int i = 0; i < 4; ++i) {
                int row = n0 + lrow[m][i];
                bool ok = row < NN;
#pragma unroll
                for (int n = 0; n < 2; ++n) {
                    float r = ok ? __bfloat162float(hres[(size_t)row * DM + gcol[n]]) : 0.f;
                    acc1[m][n][i] += b_[n] + r;
                }
            }
    }
#pragma unroll
    for (int m = 0; m < 3; ++m)
#pragma unroll
        for (int i = 0; i < 4; ++i) {
            float s = acc1[m][0][i] + acc1[m][1][i];
            float q = acc1[m][0][i] * acc1[m][0][i] + acc1[m][1][i] * acc1[m][1][i];
            s += __shfl_xor(s, 1); s += __shfl_xor(s, 2); s += __shfl_xor(s, 4); s += __shfl_xor(s, 8);
            q += __shfl_xor(q, 1); q += __shfl_xor(q, 2); q += __shfl_xor(q, 4); q += __shfl_xor(q, 8);
            if (lr == 0) { redS1[wc * ROWS + lrow[m][i]] = s; redQ1[wc * ROWS + lrow[m][i]] = q; }
        }
    __syncthreads();                                           // B2

    // ---- P3: LN1 finalize -> h2 to smA; WRITE Wf1; ISSUE Wf2 ----
    {
        float gam[2] = { g1v[gcol[0]], g1v[gcol[1]] };
        float bet[2] = { b1v[gcol[0]], b1v[gcol[1]] };
#pragma unroll
        for (int m = 0; m < 3; ++m)
#pragma unroll
            for (int i = 0; i < 4; ++i) {
                int lw = lrow[m][i];
                float s = redS1[lw] + redS1[ROWS + lw] + redS1[2 * ROWS + lw] + redS1[3 * ROWS + lw];
                float q = redQ1[lw] + redQ1[ROWS + lw] + redQ1[2 * ROWS + lw] + redQ1[3 * ROWS + lw];
                float mean = s * 0.0078125f;
                float var  = q * 0.0078125f - mean * mean;
                float rstd = rsqrtf(var + 1e-5f);
#pragma unroll
                for (int n = 0; n < 2; ++n)
                    acc1[m][n][i] = (acc1[m][n][i] - mean) * rstd * gam[n] + bet[n];
            }
    }
#pragma unroll
    for (int m = 0; m < 3; ++m)
#pragma unroll
        for (int i = 0; i < 4; ++i) {
            int rw = lrow[m][i];
#pragma unroll
            for (int n = 0; n < 2; ++n)
                *(unsigned short*)(smA + rw * 256 + ((gcol[n] * 2) ^ ((rw & 7) << 4))) = f2bu(acc1[m][n][i]);
        }
    stage_write<128, 8>(smW, pbuf, t);            // Wf1 -> smW (256x128)
    stage_load<8>(pbuf, Wf2, t);                  // Wf2 in flight across P4
    __syncthreads();                                           // B3

    // ---- P4: GEMM2: ffmid = relu(h2 @ Wf1^T + bf1), 96x256 -> smF ----
    {
        f4 acc2[3][4];
#pragma unroll
        for (int m = 0; m < 3; ++m)
#pragma unroll
            for (int n = 0; n < 4; ++n) acc2[m][n] = (f4){0,0,0,0};
        mm2<3, 4, 4>(smA, 256, smW, 256, wr, wc, lr, lk, acc2);
        int gc2[4];
        float b_[4];
#pragma unroll
        for (int n = 0; n < 4; ++n) { gc2[n] = wc * 64 + n * 16 + lr; b_[n] = bf1[gc2[n]]; }
#pragma unroll
        for (int m = 0; m < 3; ++m)
#pragma unroll
            for (int i = 0; i < 4; ++i) {
                int rw = lrow[m][i];
#pragma unroll
                for (int n = 0; n < 4; ++n) {
                    float v = fmaxf(acc2[m][n][i] + b_[n], 0.f);
                    *(unsigned short*)(smF + rw * 512 + ((gc2[n] * 2) ^ ((rw & 7) << 4))) = f2bu(v);
                }
            }
    }
    __syncthreads();                                           // B4

    // ---- P5: WRITE Wf2; ISSUE Wq+Wk ----
    stage_write<256, 8>(smW, pbuf, t);            // Wf2 -> smW (128x256)
    uint4 qkbuf[8];
    if (doQKV) {
        stage_load<4>(*(uint4(*)[4])&qkbuf[0], Wq, t);
        stage_load<4>(*(uint4(*)[4])&qkbuf[4], Wk, t);
    }
    __syncthreads();                                           // B5

    // ---- P6: GEMM3 (K=256) + bf2 + h2(reg) residual + LN2 stats ----
    f4 acc3[3][2];
#pragma unroll
    for (int m = 0; m < 3; ++m) { acc3[m][0] = (f4){0,0,0,0}; acc3[m][1] = (f4){0,0,0,0}; }
    mm2<3, 2, 8>(smF, 512, smW, 512, wr, wc, lr, lk, acc3);
    {
        float b_[2] = { bf2[gcol[0]], bf2[gcol[1]] };
#pragma unroll
        for (int m = 0; m < 3; ++m)
#pragma unroll
            for (int i = 0; i < 4; ++i)
#pragma unroll
                for (int n = 0; n < 2; ++n)
                    acc3[m][n][i] += b_[n] + acc1[m][n][i];
    }
#pragma unroll
    for (int m = 0; m < 3; ++m)
#pragma unroll
        for (int i = 0; i < 4; ++i) {
            float s = acc3[m][0][i] + acc3[m][1][i];
            float q = acc3[m][0][i] * acc3[m][0][i] + acc3[m][1][i] * acc3[m][1][i];
            s += __shfl_xor(s, 1); s += __shfl_xor(s, 2); s += __shfl_xor(s, 4); s += __shfl_xor(s, 8);
            q += __shfl_xor(q, 1); q += __shfl_xor(q, 2); q += __shfl_xor(q, 4); q += __shfl_xor(q, 8);
            if (lr == 0) { redS2[wc * ROWS + lrow[m][i]] = s; redQ2[wc * ROWS + lrow[m][i]] = q; }
        }
    __syncthreads();                                           // B6

    // ---- P7: LN2 finalize + h stores; WRITE Wq/Wk; ISSUE Wv ----
    {
        float gam[2] = { g2v[gcol[0]], g2v[gcol[1]] };
        float bet[2] = { b2v[gcol[0]], b2v[gcol[1]] };
#pragma unroll
        for (int m = 0; m < 3; ++m)
#pragma unroll
            for (int i = 0; i < 4; ++i) {
                int lw = lrow[m][i];
                float s = redS2[lw] + redS2[ROWS + lw] + redS2[2 * ROWS + lw] + redS2[3 * ROWS + lw];
                float q = redQ2[lw] + redQ2[ROWS + lw] + redQ2[2 * ROWS + lw] + redQ2[3 * ROWS + lw];
                float mean = s * 0.0078125f;
                float var  = q * 0.0078125f - mean * mean;
                float rstd = rsqrtf(var + 1e-5f);
                int row = n0 + lw;
#pragma unroll
                for (int n = 0; n < 2; ++n) {
                    float o = (acc3[m][n][i] - mean) * rstd * gam[n] + bet[n];
                    acc3[m][n][i] = o;
                    if (row < NN) {
                        hres[(size_t)row * DM + gcol[n]] = __float2bfloat16(o);
                        if (hout_f) hout_f[(size_t)row * DM + gcol[n]] = o;
                    }
                }
            }
    }
    if (!doQKV) return;
    stage_write<128, 4>(smW,         *(uint4(*)[4])&qkbuf[0], t);   // Wq -> smW[0:32K)
    stage_write<128, 4>(smW + 32768, *(uint4(*)[4])&qkbuf[4], t);   // Wk -> smW[32K:64K)
    stage_load<4>(*(uint4(*)[4])&pbuf[0], Wv, t);                   // Wv in flight
    __syncthreads();                                           // B7

    // ---- P8: h_new -> smA (stats dead); WRITE Wv -> smF ----
#pragma unroll
    for (int m = 0; m < 3; ++m)
#pragma unroll
        for (int i = 0; i < 4; ++i) {
            int rw = lrow[m][i];
#pragma unroll
            for (int n = 0; n < 2; ++n)
                *(unsigned short*)(smA + rw * 256 + ((gcol[n] * 2) ^ ((rw & 7) << 4))) = f2bu(acc3[m][n][i]);
        }
    stage_write<128, 4>(smF, *(uint4(*)[4])&pbuf[0], t);
    __syncthreads();                                           // B8

    // ---- P9: GEMM_Q + GEMM_K + GEMM_V (one phase, no more barriers) ----
    {
        f4 aq[3][2];
#pragma unroll
        for (int m = 0; m < 3; ++m) { aq[m][0] = (f4){0,0,0,0}; aq[m][1] = (f4){0,0,0,0}; }
        mm2<3, 2, 4>(smA, 256, smW, 256, wr, wc, lr, lk, aq);
        float b_[2] = { bqv[gcol[0]], bqv[gcol[1]] };
#pragma unroll
        for (int m = 0; m < 3; ++m)
#pragma unroll
            for (int i = 0; i < 4; ++i) {
                int row = n0 + lrow[m][i];
                if (row < NN)
#pragma unroll
                    for (int n = 0; n < 2; ++n)
                        Qo[(size_t)row * DM + gcol[n]] = __float2bfloat16(aq[m][n][i] + b_[n]);
            }
    }
    {
        f4 ak[3][2];
#pragma unroll
        for (int m = 0; m < 3; ++m) { ak[m][0] = (f4){0,0,0,0}; ak[m][1] = (f4){0,0,0,0}; }
        mm2<3, 2, 4>(smA, 256, smW + 32768, 256, wr, wc, lr, lk, ak);
        float b_[2] = { bkv[gcol[0]], bkv[gcol[1]] };
#pragma unroll
        for (int m = 0; m < 3; ++m)
#pragma unroll
            for (int i = 0; i < 4; ++i) {
                int row = n0 + lrow[m][i];
                if (row < NN)
#pragma unroll
                    for (int n = 0; n < 2; ++n)
                        Ko[(size_t)row * DM + gcol[n]] = f2fp8(ak[m][n][i] + b_[n]);
            }
    }
    {
        f4 av_[3][2];
#pragma unroll
        for (int m = 0; m < 3; ++m) { av_[m][0] = (f4){0,0,0,0}; av_[m][1] = (f4){0,0,0,0}; }
        mm2<3, 2, 4>(smA, 256, smF, 256, wr, wc, lr, lk, av_);
        float b_[2] = { bvv[gcol[0]], bvv[gcol[1]] };
#pragma unroll
        for (int m = 0; m < 3; ++m)
#pragma unroll
            for (int i = 0; i < 4; ++i) {
                int row = n0 + lrow[m][i];
                if (row < NN)
#pragma unroll
                    for (int n = 0; n < 2; ++n)
                        Vo[(size_t)row * DM + gcol[n]] = f2fp8(av_[m][n][i] + b_[n]);
            }
    }
}

// ---------------- edge attention: fp8 K/V, 8 lanes per edge (one head per lane) ----------------
__global__ __launch_bounds__(256)
void attn_k(const bf16* __restrict__ Q, const unsigned char* __restrict__ K8,
            const unsigned char* __restrict__ V8, const int* __restrict__ row_ptr,
            const int* __restrict__ csr, bf16* __restrict__ out)
{
    int lane = threadIdx.x & 63;
    int n = blockIdx.x * 4 + (threadIdx.x >> 6);
    int g = lane >> 3, sub = lane & 7;
    const uint4* K4 = (const uint4*)K8;
    const uint4* V4 = (const uint4*)V8;
    float q[16];
    {
        const uint4* Q4 = (const uint4*)Q;
        uint4 qa = Q4[n * 16 + sub * 2];
        uint4 qb = Q4[n * 16 + sub * 2 + 1];
        up8(qa, q); up8(qb, q + 8);
    }
    int e0 = row_ptr[n], e1 = row_ptr[n + 1];
    float acc[16];
#pragma unroll
    for (int j = 0; j < 16; ++j) acc[j] = 0.f;
    float zacc = 0.f;

    int sA = (e0 + g < e1) ? csr[e0 + g] : 0;
    uint4 k0 = K4[(size_t)sA * 8 + sub];
    uint4 v0 = V4[(size_t)sA * 8 + sub];
    int sB = (e0 + 8 + g < e1) ? csr[e0 + 8 + g] : 0;
    uint4 k1 = K4[(size_t)sB * 8 + sub];
    uint4 v1 = V4[(size_t)sB * 8 + sub];
    for (int base = e0; base < e1; base += 8) {
        int en = base + 16 + g;
        int s2 = (en < e1) ? csr[en] : 0;
        uint4 k2 = K4[(size_t)s2 * 8 + sub];      // 2-deep prefetch
        uint4 v2 = V4[(size_t)s2 * 8 + sub];
        float kf[16];
        fp8x4(k0.x, kf); fp8x4(k0.y, kf + 4); fp8x4(k0.z, kf + 8); fp8x4(k0.w, kf + 12);
        float p = 0.f;
#pragma unroll
        for (int j = 0; j < 16; ++j) p = fmaf(q[j], kf[j], p);
        float sc = __expf(fminf(fmaxf(p * 0.25f, -10.f), 10.f)) * 0.5f;
        if (base + g >= e1) sc = 0.f;
        float vf[16];
        fp8x4(v0.x, vf); fp8x4(v0.y, vf + 4); fp8x4(v0.z, vf + 8); fp8x4(v0.w, vf + 12);
#pragma unroll
        for (int j = 0; j < 16; ++j) acc[j] = fmaf(sc, vf[j], acc[j]);
        zacc += sc;
        k0 = k1; v0 = v1; k1 = k2; v1 = v2;
    }
#pragma unroll
    for (int j = 0; j < 16; ++j) {
        acc[j] += __shfl_xor(acc[j], 8);
        acc[j] += __shfl_xor(acc[j], 16);
        acc[j] += __shfl_xor(acc[j], 32);
    }
    zacc += __shfl_xor(zacc, 8);
    zacc += __shfl_xor(zacc, 16);
    zacc += __shfl_xor(zacc, 32);
    float inv = 1.f / (zacc + 1e-6f);
    if (g == 0) {
        uint4 o1, o2;
        o1.x = pk2(acc[0] * inv, acc[1] * inv);
        o1.y = pk2(acc[2] * inv, acc[3] * inv);
        o1.z = pk2(acc[4] * inv, acc[5] * inv);
        o1.w = pk2(acc[6] * inv, acc[7] * inv);
        o2.x = pk2(acc[8] * inv, acc[9] * inv);
        o2.y = pk2(acc[10] * inv, acc[11] * inv);
        o2.z = pk2(acc[12] * inv, acc[13] * inv);
        o2.w = pk2(acc[14] * inv, acc[15] * inv);
        ((uint4*)out)[n * 16 + sub * 2] = o1;
        ((uint4*)out)[n * 16 + sub * 2 + 1] = o2;
    }
}

// ---------------- host side ----------------
static inline void g1(hipStream_t st, const bf16* A, const bf16* A2, const bf16* W,
                      const float* bia, float* Cf, bf16* Cb, int N, int K, int M, int post)
{
    dim3 grid((N + 63) / 64, M / 128, 1);
    gemm_k<<<grid, 256, 0, st>>>(A, A2, W, nullptr, nullptr, bia, nullptr, nullptr,
                                 Cf, Cb, nullptr, nullptr, nullptr, nullptr, N, K, M, post);
}

static inline void g3(hipStream_t st, const bf16* A,
                      const bf16* W0, const float* b0, bf16* C0,
                      const bf16* W1, const float* b1, unsigned char* C1,
                      const bf16* W2, const float* b2, unsigned char* C2,
                      int N, int K, int M)
{
    dim3 grid((N + 63) / 64, M / 128, 3);
    gemm_k<<<grid, 256, 0, st>>>(A, nullptr, W0, W1, W2, b0, b1, b2,
                                 nullptr, C0, nullptr, nullptr, C1, C2, N, K, M, 0);
}

extern "C" void kernel_launch(void* const* d_in, const int* in_sizes, int n_in,
                              void* d_out, int out_size, void* d_ws, size_t ws_size,
                              hipStream_t stream)
{
    const float* x    = (const float*)d_in[0];
    const float* Iin  = (const float*)d_in[1];
    const int*   src  = (const int*)d_in[2];
    const int*   dst  = (const int*)d_in[3];
    const float* Wemb = (const float*)d_in[4];
    const float* Wq   = (const float*)d_in[5];  const float* bq  = (const float*)d_in[6];
    const float* Wk   = (const float*)d_in[7];  const float* bk  = (const float*)d_in[8];
    const float* Wv   = (const float*)d_in[9];  const float* bv  = (const float*)d_in[10];
    const float* Wi   = (const float*)d_in[11]; const float* bi  = (const float*)d_in[12];
    const float* Wo   = (const float*)d_in[13]; const float* bo  = (const float*)d_in[14];
    const float* g1g  = (const float*)d_in[15]; const float* be1 = (const float*)d_in[16];
    const float* g2g  = (const float*)d_in[17]; const float* be2 = (const float*)d_in[18];
    const float* Wf1  = (const float*)d_in[19]; const float* bf1 = (const float*)d_in[20];
    const float* Wf2  = (const float*)d_in[21]; const float* bf2 = (const float*)d_in[22];
    const float* Wm1  = (const float*)d_in[23]; const float* bm1 = (const float*)d_in[24];
    const float* Wm2  = (const float*)d_in[25]; const float* bm2 = (const float*)d_in[26];

    const size_t NF = (size_t)NN * DM;          // 2,560,000
    bf16* B      = (bf16*)d_ws;
    bf16* h_b    = B;                           // bf16 residual stream (in-place updated)
    bf16* Qb     = B + NF;
    unsigned char* K8 = (unsigned char*)(B + 2 * NF);   // N x 128 fp8
    unsigned char* V8 = (unsigned char*)(B + 3 * NF);
    bf16* attn_b = B + 4 * NF;
    bf16* Iw_b   = B + 5 * NF;
    bf16* wts    = B + 6 * NF;
    bf16* Wemb_b = wts;                 // 32768
    bf16* Wq_b   = wts + 32768;         // 16384
    bf16* Wk_b   = Wq_b + 16384;
    bf16* Wv_b   = Wk_b + 16384;
    bf16* Wo_b   = Wv_b + 16384;
    bf16* Wi_b   = Wo_b + 16384;        // 8192
    bf16* Wf1_b  = Wi_b + 8192;         // 32768
    bf16* Wf2_b  = Wf1_b + 32768;       // 32768
    bf16* Wm1_b  = Wf2_b + 32768;       // 16384
    bf16* Wm2_b  = Wm1_b + 16384;       // 32768
    bf16* wend   = Wm2_b + 32768;
    bf16* x_b    = Qb;                  // N x 256 (spans Qb + K8 slots), dead after embed
    bf16* Iin_b  = B + 3 * NF;          // N x 64 in V8 slot, dead before QKV0
    bf16* tmp_b  = Qb;                  // head mid (N x 128), Qb dead after last attn
    int* ib      = (int*)wend;
    int* cnt     = ib;
    int* cnt2    = ib + NN;
    int* row_ptr = ib + 2 * NN;
    int* csr     = ib + 3 * NN + 1;
    int* part    = csr + NE;
    int* bsum    = part + NN;
    int* carry   = bsum + 32;
    int* total   = carry + 32;

    // ---- CSR build (once per call) ----
    hipMemsetAsync(cnt,  0, NN * sizeof(int), stream);
    hipMemsetAsync(cnt2, 0, NN * sizeof(int), stream);
    hist_k<<<(NE + 255) / 256, 256, 0, stream>>>(dst, cnt, NE);
    const int nsb = (NN + 1023) / 1024;
    scan1_k<<<nsb, 1024, 0, stream>>>(cnt, part, bsum, NN);
    scan2_k<<<1, 64, 0, stream>>>(bsum, carry, nsb, total);
    scan3_k<<<(NN + 256) / 256, 256, 0, stream>>>(part, carry, total, row_ptr, NN);
    scatter_k<<<(NE + 255) / 256, 256, 0, stream>>>(src, dst, row_ptr, cnt2, csr, NE);

    // ---- batched f32->bf16 conversion of x, I, and all weights ----
    Cvt c;
    c.s[0] = x;    c.d[0] = x_b;    c.n[0] = NN * DIN;
    c.s[1] = Iin;  c.d[1] = Iin_b;  c.n[1] = NN * 64;
    c.s[2] = Wemb; c.d[2] = Wemb_b; c.n[2] = 32768;
    c.s[3] = Wq;   c.d[3] = Wq_b;   c.n[3] = 16384;
    c.s[4] = Wk;   c.d[4] = Wk_b;   c.n[4] = 16384;
    c.s[5] = Wv;   c.d[5] = Wv_b;   c.n[5] = 16384;
    c.s[6] = Wo;   c.d[6] = Wo_b;   c.n[6] = 16384;
    c.s[7] = Wi;   c.d[7] = Wi_b;   c.n[7] = 8192;
    c.s[8] = Wf1;  c.d[8] = Wf1_b;  c.n[8] = 32768;
    c.s[9] = Wf2;  c.d[9] = Wf2_b;  c.n[9] = 32768;
    c.s[10] = Wm1; c.d[10] = Wm1_b; c.n[10] = 16384;
    c.s[11] = Wm2; c.d[11] = Wm2_b; c.n[11] = 32768;
    cvt_many_k<<<dim3(640, 12), 256, 0, stream>>>(c);

    // ---- prologue: embed, Iw, first-layer QKV (K/V straight to fp8) ----
    g1(stream, x_b,   nullptr, Wemb_b, nullptr, nullptr, h_b, NN, DIN, DM, 0);
    g1(stream, Iin_b, nullptr, Wi_b, bi, nullptr, Iw_b, NN, 64, DM, 0);
    g3(stream, h_b, Wq_b, bq, Qb, Wk_b, bk, K8, Wv_b, bv, V8, NN, DM, DM);

    // ---- 10 shared-weight layers: attn + mega-fused ----
    const int nblk = (NN + ROWS - 1) / ROWS;    // 209 <= 256 -> single round
    for (int l = 0; l < 10; ++l) {
        attn_k<<<NN / 4, 256, 0, stream>>>(Qb, K8, V8, row_ptr, csr, attn_b);
        layer_k<<<nblk, 512, 139264, stream>>>(
            attn_b, Iw_b, h_b, (l == 9) ? (float*)d_out : nullptr,
            Qb, K8, V8, (l < 9) ? 1 : 0,
            Wo_b, bo, Wf1_b, bf1, Wf2_b, bf2,
            Wq_b, bq, Wk_b, bk, Wv_b, bv,
            g1g, be1, g2g, be2);
    }

    // ---- reconstruction head ----
    g1(stream, h_b, nullptr, Wm1_b, bm1, nullptr, tmp_b, NN, DM, DM, 2);   // selu
    float* xhat = (float*)d_out + NF;
    g1(stream, tmp_b, nullptr, Wm2_b, bm2, xhat, nullptr, NN, DM, DIN, 0);
}

// Round 14
// 687.274 us; speedup vs baseline: 1.1468x; 1.1422x over previous
//
#include <hip/hip_runtime.h>
#include <hip/hip_bf16.h>

#define NN 20000      // nodes
#define NE 640000     // edges
#define DIN 256
#define DM  128
#define ROWS 96       // rows per layer_k block (209 blocks -> single scheduling round)

typedef __hip_bfloat16 bf16;
typedef __attribute__((ext_vector_type(8))) short s8;     // 8 bf16 (4 VGPRs) MFMA frag
typedef __attribute__((ext_vector_type(4))) float f4;     // 4 f32 acc
typedef __attribute__((ext_vector_type(2))) float fl2;

__device__ __forceinline__ float bu2f_lo(unsigned u) { union {unsigned u; float f;} c; c.u = u << 16; return c.f; }
__device__ __forceinline__ float bu2f_hi(unsigned u) { union {unsigned u; float f;} c; c.u = u & 0xffff0000u; return c.f; }
__device__ __forceinline__ unsigned short f2bu(float f) { bf16 t = __float2bfloat16(f); return *reinterpret_cast<unsigned short*>(&t); }
__device__ __forceinline__ unsigned pk2(float lo, float hi) { return (unsigned)f2bu(lo) | ((unsigned)f2bu(hi) << 16); }
__device__ __forceinline__ unsigned addpk(unsigned a, unsigned b) {
    return pk2(bu2f_lo(a) + bu2f_lo(b), bu2f_hi(a) + bu2f_hi(b));
}
__device__ __forceinline__ void up8(uint4 u, float* f) {
    f[0] = bu2f_lo(u.x); f[1] = bu2f_hi(u.x);
    f[2] = bu2f_lo(u.y); f[3] = bu2f_hi(u.y);
    f[4] = bu2f_lo(u.z); f[5] = bu2f_hi(u.z);
    f[6] = bu2f_lo(u.w); f[7] = bu2f_hi(u.w);
}

// ---------------- fp8 e4m3 (OCP) helpers ----------------
#if defined(__has_builtin)
#if __has_builtin(__builtin_amdgcn_cvt_pk_f32_fp8) && __has_builtin(__builtin_amdgcn_cvt_pk_fp8_f32)
#define HW_FP8 1
#endif
#if __has_builtin(__builtin_amdgcn_global_load_lds)
#define HAS_GLL 1
#endif
#endif

__device__ __forceinline__ void fp8x4(unsigned u, float* o) {
#ifdef HW_FP8
    fl2 lo = __builtin_amdgcn_cvt_pk_f32_fp8((int)u, false);
    fl2 hi = __builtin_amdgcn_cvt_pk_f32_fp8((int)u, true);
    o[0] = lo[0]; o[1] = lo[1]; o[2] = hi[0]; o[3] = hi[1];
#else
#pragma unroll
    for (int i = 0; i < 4; ++i) {
        unsigned b = (u >> (8 * i)) & 0xffu;
        unsigned w = ((b & 0x80u) << 24) | ((b & 0x7fu) << 20);
        o[i] = __uint_as_float(w) * 1.3292279957849159e36f;   // x2^120
    }
#endif
}

__device__ __forceinline__ unsigned char f2fp8(float v) {
#ifdef HW_FP8
    int r = __builtin_amdgcn_cvt_pk_fp8_f32(v, 0.f, 0, false);
    return (unsigned char)(r & 0xff);
#else
    float a = fabsf(v);
    unsigned s = (__float_as_uint(v) >> 24) & 0x80u;
    a = fminf(a, 448.f);
    unsigned out;
    if (a < 0.0009765625f) {
        out = 0;
    } else if (a < 0.015625f) {
        int q = (int)(a * 512.f + 0.5f);
        out = (unsigned)q;
    } else {
        unsigned bits = __float_as_uint(a);
        int e = (int)((bits >> 23) & 0xff) - 127;
        unsigned m = bits & 0x7fffffu;
        unsigned mr = m + 0x7ffffu + ((m >> 20) & 1u);
        if (mr >> 23) { mr = 0; e += 1; } else mr >>= 20;
        if (e > 8) { e = 8; mr = 7; }
        out = ((unsigned)(e + 7) << 3) | (mr & 7u);
    }
    return (unsigned char)(out | s);
#endif
}

// ---------------- CSR build (dst-sorted edge list) ----------------
__global__ void hist_k(const int* __restrict__ dst, int* __restrict__ cnt, int E) {
    int e = blockIdx.x * 256 + threadIdx.x;
    if (e < E) atomicAdd(&cnt[dst[e]], 1);
}

__global__ void scan1_k(const int* __restrict__ cnt, int* __restrict__ part,
                        int* __restrict__ bsum, int n) {
    __shared__ int lds[1024];
    int b = blockIdx.x, t = threadIdx.x, i = b * 1024 + t;
    int v = (i < n) ? cnt[i] : 0;
    lds[t] = v;
    __syncthreads();
    for (int off = 1; off < 1024; off <<= 1) {
        int x = (t >= off) ? lds[t - off] : 0;
        __syncthreads();
        lds[t] += x;
        __syncthreads();
    }
    if (i < n) part[i] = lds[t] - v;
    if (t == 1023) bsum[b] = lds[t];
}

__global__ void scan2_k(const int* __restrict__ bsum, int* __restrict__ carry,
                        int nb, int* __restrict__ total) {
    if (threadIdx.x == 0) {
        int c = 0;
        for (int b = 0; b < nb; ++b) { carry[b] = c; c += bsum[b]; }
        total[0] = c;
    }
}

__global__ void scan3_k(const int* __restrict__ part, const int* __restrict__ carry,
                        const int* __restrict__ total, int* __restrict__ row_ptr, int n) {
    int i = blockIdx.x * 256 + threadIdx.x;
    if (i < n) row_ptr[i] = part[i] + carry[i >> 10];
    else if (i == n) row_ptr[n] = total[0];
}

__global__ void scatter_k(const int* __restrict__ src, const int* __restrict__ dst,
                          const int* __restrict__ row_ptr, int* __restrict__ cnt2,
                          int* __restrict__ csr_src, int E) {
    int e = blockIdx.x * 256 + threadIdx.x;
    if (e < E) {
        int d = dst[e];
        int pos = row_ptr[d] + atomicAdd(&cnt2[d], 1);
        csr_src[pos] = src[e];
    }
}

// ---------------- batched f32 -> bf16 convert ----------------
struct Cvt { const float* s[12]; bf16* d[12]; int n[12]; };

__global__ void cvt_many_k(Cvt c) {
    int a = blockIdx.y;
    int n4 = c.n[a] >> 2;
    const float4* s = (const float4*)c.s[a];
    uint2* d = (uint2*)c.d[a];
    for (int i = blockIdx.x * 256 + threadIdx.x; i < n4; i += gridDim.x * 256) {
        float4 v = s[i];
        d[i] = make_uint2(pk2(v.x, v.y), pk2(v.z, v.w));
    }
}

// ---------------- shared GEMM helpers ----------------
template<int MR, int NF, int NKS>
__device__ __forceinline__ void mm2(const char* A, int rbA, const char* W, int rbW,
                                    int wr, int wc, int lr, int lk, f4 (&acc)[MR][NF])
{
#pragma unroll
    for (int ks = 0; ks < NKS; ++ks) {
        int w = ks * 64 + (lk << 4);
        s8 af[MR], wf[NF];
#pragma unroll
        for (int m = 0; m < MR; ++m) {
            int ar = wr * (MR * 16) + m * 16 + lr;
            af[m] = *(const s8*)(A + ar * rbA + (w ^ ((ar & 7) << 4)));
        }
#pragma unroll
        for (int n = 0; n < NF; ++n) {
            int wrow = wc * (NF << 4) + n * 16 + lr;
            wf[n] = *(const s8*)(W + wrow * rbW + (w ^ ((wrow & 7) << 4)));
        }
#pragma unroll
        for (int m = 0; m < MR; ++m)
#pragma unroll
            for (int n = 0; n < NF; ++n)
                acc[m][n] = __builtin_amdgcn_mfma_f32_16x16x32_bf16(af[m], wf[n], acc[m][n], 0, 0, 0);
    }
}

// direct stage (load+swizzled LDS write), 512 thr -- fallback path
template<int R, int KK>
__device__ __forceinline__ void stage_w(char* dst, const bf16* __restrict__ W, int t) {
    constexpr int K8 = KK / 8;
    constexpr int SH = (K8 == 16) ? 4 : 5;
#pragma unroll 2
    for (int f = t; f < R * K8; f += 512) {
        int r = f >> SH, k8 = f & (K8 - 1);
        uint4 wv = *(const uint4*)&W[(size_t)r * KK + (k8 << 3)];
        *(uint4*)(dst + r * (KK * 2) + ((k8 << 4) ^ ((r & 7) << 4))) = wv;
    }
}

// global_load_lds weight stage: LINEAR LDS dest (wave-uniform base + lane*16),
// pre-swizzled per-lane GLOBAL source (XOR involution on the 16B-slot index).
// LDS[r][j] = W[r][j ^ (r&7)]; mm2's read XOR recovers W[r][w]. Zero VGPR round-trip.
template<int KK, int NLD>
__device__ __forceinline__ void stage_lds(char* dst, const bf16* __restrict__ W, int t) {
    constexpr int K8 = KK / 8;
    constexpr int SH = (K8 == 16) ? 4 : 5;
#ifdef HAS_GLL
#pragma unroll
    for (int j = 0; j < NLD; ++j) {
        int f = t + j * 512;
        int r = f >> SH, k8 = f & (K8 - 1);
        int srcslot = r * K8 + (k8 ^ (r & 7));
        __builtin_amdgcn_global_load_lds(
            (const __attribute__((address_space(1))) unsigned int*)(const void*)((const uint4*)W + srcslot),
            (__attribute__((address_space(3))) unsigned int*)(void*)(dst + f * 16),
            16, 0, 0);
    }
#else
#pragma unroll
    for (int j = 0; j < NLD; ++j) {
        int f = t + j * 512;
        int r = f >> SH, k8 = f & (K8 - 1);
        uint4 wv = *(const uint4*)&W[(size_t)r * KK + (k8 << 3)];
        *(uint4*)(dst + r * (KK * 2) + ((k8 << 4) ^ ((r & 7) << 4))) = wv;
    }
#endif
}

// ---------------- bf16 MFMA GEMM, 64x128 tile (prologue / head) ----------------
__global__ __launch_bounds__(256, 2)
void gemm_k(const bf16* __restrict__ A, const bf16* __restrict__ A2,
            const bf16* __restrict__ W0, const bf16* __restrict__ W1, const bf16* __restrict__ W2,
            const float* __restrict__ b0, const float* __restrict__ b1, const float* __restrict__ b2,
            float* __restrict__ Cf0,
            bf16* __restrict__ Cb0, bf16* __restrict__ Cb1, bf16* __restrict__ Cb2,
            unsigned char* __restrict__ C81, unsigned char* __restrict__ C82,
            int N, int K, int M, int post)
{
    __shared__ unsigned short Al[64 * 128];
    __shared__ unsigned short Wl[128 * 128];
    int z = blockIdx.z;
    const bf16* W    = (z == 0) ? W0 : (z == 1 ? W1 : W2);
    const float* bia = (z == 0) ? b0 : (z == 1 ? b1 : b2);
    bf16*  Cb        = (z == 0) ? Cb0 : (z == 1 ? Cb1 : Cb2);
    float* Cf        = (z == 0) ? Cf0 : nullptr;
    unsigned char* C8 = (z == 1) ? C81 : (z == 2 ? C82 : nullptr);
    int n0 = blockIdx.x * 64, moff = blockIdx.y * 128;
    int t = threadIdx.x;
    int lane = t & 63, wid = t >> 6;
    int wr = wid >> 1, wc = wid & 1;
    int lr = lane & 15, lk = lane >> 4;

    f4 acc[2][4];
#pragma unroll
    for (int m = 0; m < 2; ++m)
#pragma unroll
        for (int n = 0; n < 4; ++n) acc[m][n] = (f4){0.f, 0.f, 0.f, 0.f};

    const char* Ac = (const char*)Al;
    const char* Wc = (const char*)Wl;

    for (int koff = 0; koff < K; koff += 128) {
        int chunk = (K - koff < 128) ? (K - koff) : 128;
        int ksh = (chunk == 64) ? 3 : 4;
        int k8s = 1 << ksh;
        int rowb = chunk * 2;
        for (int f = t; f < (64 << ksh); f += 256) {
            int r = f >> ksh, k8 = f & (k8s - 1);
            int row = n0 + r;
            uint4 av = make_uint4(0, 0, 0, 0);
            if (row < N) {
                av = *(const uint4*)&A[(size_t)row * K + koff + (k8 << 3)];
                if (A2) {
                    uint4 a2 = *(const uint4*)&A2[(size_t)row * K + koff + (k8 << 3)];
                    av.x = addpk(av.x, a2.x); av.y = addpk(av.y, a2.y);
                    av.z = addpk(av.z, a2.z); av.w = addpk(av.w, a2.w);
                }
            }
            *(uint4*)((char*)Al + r * rowb + ((k8 << 4) ^ ((r & 7) << 4))) = av;
        }
        for (int f = t; f < (128 << ksh); f += 256) {
            int r = f >> ksh, k8 = f & (k8s - 1);
            uint4 wv = *(const uint4*)&W[(size_t)(moff + r) * K + koff + (k8 << 3)];
            *(uint4*)((char*)Wl + r * rowb + ((k8 << 4) ^ ((r & 7) << 4))) = wv;
        }
        __syncthreads();
        int nks = chunk >> 5;
        for (int ks = 0; ks < nks; ++ks) {
            int w = ks * 64 + (lk << 4);
            s8 af[2], wf[4];
#pragma unroll
            for (int m = 0; m < 2; ++m) {
                int ar = wr * 32 + m * 16 + lr;
                af[m] = *(const s8*)(Ac + ar * rowb + (w ^ ((ar & 7) << 4)));
            }
#pragma unroll
            for (int n = 0; n < 4; ++n) {
                int wrow = wc * 64 + n * 16 + lr;
                wf[n] = *(const s8*)(Wc + wrow * rowb + (w ^ ((wrow & 7) << 4)));
            }
#pragma unroll
            for (int m = 0; m < 2; ++m)
#pragma unroll
                for (int n = 0; n < 4; ++n)
                    acc[m][n] = __builtin_amdgcn_mfma_f32_16x16x32_bf16(af[m], wf[n], acc[m][n], 0, 0, 0);
        }
        __syncthreads();
    }

    int gcol[4];
#pragma unroll
    for (int n = 0; n < 4; ++n) gcol[n] = moff + wc * 64 + n * 16 + lr;
    float bias_[4];
#pragma unroll
    for (int n = 0; n < 4; ++n) bias_[n] = bia ? bia[gcol[n]] : 0.f;
#pragma unroll
    for (int m = 0; m < 2; ++m)
#pragma unroll
        for (int i = 0; i < 4; ++i) {
            int row = n0 + wr * 32 + m * 16 + lk * 4 + i;
            if (row < N) {
#pragma unroll
                for (int n = 0; n < 4; ++n) {
                    float v = acc[m][n][i] + bias_[n];
                    if (post == 1) v = fmaxf(v, 0.f);
                    else if (post == 2) v = (v > 0.f) ? 1.0507009873554805f * v
                                                      : 1.7580993408473766f * expm1f(v);
                    if (Cf) Cf[(size_t)row * M + gcol[n]] = v;
                    if (Cb) Cb[(size_t)row * M + gcol[n]] = __float2bfloat16(v);
                    if (C8) C8[(size_t)row * M + gcol[n]] = f2fp8(v);
                }
            }
        }
}

// ---------------- mega-fused layer kernel: gload_lds staging, 8 barriers ----------------
// 96 rows/block, 512 thr, 136 KB LDS, single block-round. Weight staging via
// global_load_lds (zero VGPR; linear LDS dest + pre-swizzled source). Issued at the
// top of each phase so DMA flies under the phase's VALU work. No reg prefetch
// (R12/R13: compiler pins VGPR=128 -> spills).
__global__ __launch_bounds__(512, 1)
void layer_k(const bf16* __restrict__ attn_b, const bf16* __restrict__ Iw,
             bf16* __restrict__ hres, float* __restrict__ hout_f,
             bf16* __restrict__ Qo, unsigned char* __restrict__ Ko,
             unsigned char* __restrict__ Vo, int doQKV,
             const bf16* __restrict__ Wo, const float* __restrict__ bo,
             const bf16* __restrict__ Wf1, const float* __restrict__ bf1,
             const bf16* __restrict__ Wf2, const float* __restrict__ bf2,
             const bf16* __restrict__ Wq, const float* __restrict__ bqv,
             const bf16* __restrict__ Wk, const float* __restrict__ bkv,
             const bf16* __restrict__ Wv, const float* __restrict__ bvv,
             const float* __restrict__ g1v, const float* __restrict__ b1v,
             const float* __restrict__ g2v, const float* __restrict__ b2v)
{
    extern __shared__ char sm[];
    char* smA = sm;                  // 24K  (96 rows x 256 B)
    char* smW = sm + 24576;          // 64K
    char* smF = sm + 90112;          // 48K  (96 rows x 512 B)
    float* redS1 = (float*)smF;      // LN1 stats: F dead until P4
    float* redQ1 = redS1 + 384;
    float* redS2 = (float*)smA;      // LN2 stats: A dead after GEMM2
    float* redQ2 = redS2 + 384;

    int n0 = blockIdx.x * ROWS;
    int t = threadIdx.x;
    int lane = t & 63, wid = t >> 6;
    int wr = wid >> 2, wc = wid & 3;             // 2 x 4 wave grid
    int lr = lane & 15, lk = lane >> 4;
    int gcol[2] = { wc * 32 + lr, wc * 32 + 16 + lr };
    int lrow[3][4];
#pragma unroll
    for (int m = 0; m < 3; ++m)
#pragma unroll
        for (int i = 0; i < 4; ++i) lrow[m][i] = wr * 48 + m * 16 + lk * 4 + i;

    // ---- P1: issue Wo DMA; stage A_in = attn + Iw (reg path, has compute) ----
    stage_lds<128, 4>(smW, Wo, t);
    for (int f = t; f < ROWS * 16; f += 512) {
        int r = f >> 4, k8 = f & 15;
        int row = n0 + r;
        uint4 av = make_uint4(0, 0, 0, 0);
        if (row < NN) {
            av = *(const uint4*)&attn_b[(size_t)row * DM + (k8 << 3)];
            uint4 a2 = *(const uint4*)&Iw[(size_t)row * DM + (k8 << 3)];
            av.x = addpk(av.x, a2.x); av.y = addpk(av.y, a2.y);
            av.z = addpk(av.z, a2.z); av.w = addpk(av.w, a2.w);
        }
        *(uint4*)(smA + r * 256 + ((k8 << 4) ^ ((r & 7) << 4))) = av;
    }
    __syncthreads();                                           // B1

    // ---- P2: GEMM1 + bo + h residual + LN1 stats ----
    f4 acc1[3][2];
#pragma unroll
    for (int m = 0; m < 3; ++m) { acc1[m][0] = (f4){0,0,0,0}; acc1[m][1] = (f4){0,0,0,0}; }
    mm2<3, 2, 4>(smA, 256, smW, 256, wr, wc, lr, lk, acc1);
    {
        float b_[2] = { bo[gcol[0]], bo[gcol[1]] };
#pragma unroll
        for (int m = 0; m < 3; ++m)
#pragma unroll
            for (int i = 0; i < 4; ++i) {
                int row = n0 + lrow[m][i];
                bool ok = row < NN;
#pragma unroll
                for (int n = 0; n < 2; ++n) {
                    float r = ok ? __bfloat162float(hres[(size_t)row * DM + gcol[n]]) : 0.f;
                    acc1[m][n][i] += b_[n] + r;
                }
            }
    }
#pragma unroll
    for (int m = 0; m < 3; ++m)
#pragma unroll
        for (int i = 0; i < 4; ++i) {
            float s = acc1[m][0][i] + acc1[m][1][i];
            float q = acc1[m][0][i] * acc1[m][0][i] + acc1[m][1][i] * acc1[m][1][i];
            s += __shfl_xor(s, 1); s += __shfl_xor(s, 2); s += __shfl_xor(s, 4); s += __shfl_xor(s, 8);
            q += __shfl_xor(q, 1); q += __shfl_xor(q, 2); q += __shfl_xor(q, 4); q += __shfl_xor(q, 8);
            if (lr == 0) { redS1[wc * ROWS + lrow[m][i]] = s; redQ1[wc * ROWS + lrow[m][i]] = q; }
        }
    __syncthreads();                                           // B2

    // ---- P3: issue Wf1 DMA (smW dead); LN1 finalize -> h2 to smA ----
    stage_lds<128, 8>(smW, Wf1, t);               // 256x128: K8=16 rows indexed by f>>4
    {
        float gam[2] = { g1v[gcol[0]], g1v[gcol[1]] };
        float bet[2] = { b1v[gcol[0]], b1v[gcol[1]] };
#pragma unroll
        for (int m = 0; m < 3; ++m)
#pragma unroll
            for (int i = 0; i < 4; ++i) {
                int lw = lrow[m][i];
                float s = redS1[lw] + redS1[ROWS + lw] + redS1[2 * ROWS + lw] + redS1[3 * ROWS + lw];
                float q = redQ1[lw] + redQ1[ROWS + lw] + redQ1[2 * ROWS + lw] + redQ1[3 * ROWS + lw];
                float mean = s * 0.0078125f;
                float var  = q * 0.0078125f - mean * mean;
                float rstd = rsqrtf(var + 1e-5f);
#pragma unroll
                for (int n = 0; n < 2; ++n)
                    acc1[m][n][i] = (acc1[m][n][i] - mean) * rstd * gam[n] + bet[n];
            }
    }
#pragma unroll
    for (int m = 0; m < 3; ++m)
#pragma unroll
        for (int i = 0; i < 4; ++i) {
            int rw = lrow[m][i];
#pragma unroll
            for (int n = 0; n < 2; ++n)
                *(unsigned short*)(smA + rw * 256 + ((gcol[n] * 2) ^ ((rw & 7) << 4))) = f2bu(acc1[m][n][i]);
        }
    __syncthreads();                                           // B3

    // ---- P4: GEMM2: ffmid = relu(h2 @ Wf1^T + bf1), 96x256 -> smF ----
    {
        f4 acc2[3][4];
#pragma unroll
        for (int m = 0; m < 3; ++m)
#pragma unroll
            for (int n = 0; n < 4; ++n) acc2[m][n] = (f4){0,0,0,0};
        mm2<3, 4, 4>(smA, 256, smW, 256, wr, wc, lr, lk, acc2);
        int gc2[4];
        float b_[4];
#pragma unroll
        for (int n = 0; n < 4; ++n) { gc2[n] = wc * 64 + n * 16 + lr; b_[n] = bf1[gc2[n]]; }
#pragma unroll
        for (int m = 0; m < 3; ++m)
#pragma unroll
            for (int i = 0; i < 4; ++i) {
                int rw = lrow[m][i];
#pragma unroll
                for (int n = 0; n < 4; ++n) {
                    float v = fmaxf(acc2[m][n][i] + b_[n], 0.f);
                    *(unsigned short*)(smF + rw * 512 + ((gc2[n] * 2) ^ ((rw & 7) << 4))) = f2bu(v);
                }
            }
    }
    __syncthreads();                                           // B4

    // ---- P5: issue Wf2 DMA (smW dead) ----
    stage_lds<256, 8>(smW, Wf2, t);               // 128x256: K8=32
    __syncthreads();                                           // B5

    // ---- P6: GEMM3 (K=256) + bf2 + h2(reg) residual + LN2 stats ----
    f4 acc3[3][2];
#pragma unroll
    for (int m = 0; m < 3; ++m) { acc3[m][0] = (f4){0,0,0,0}; acc3[m][1] = (f4){0,0,0,0}; }
    mm2<3, 2, 8>(smF, 512, smW, 512, wr, wc, lr, lk, acc3);
    {
        float b_[2] = { bf2[gcol[0]], bf2[gcol[1]] };
#pragma unroll
        for (int m = 0; m < 3; ++m)
#pragma unroll
            for (int i = 0; i < 4; ++i)
#pragma unroll
                for (int n = 0; n < 2; ++n)
                    acc3[m][n][i] += b_[n] + acc1[m][n][i];
    }
#pragma unroll
    for (int m = 0; m < 3; ++m)
#pragma unroll
        for (int i = 0; i < 4; ++i) {
            float s = acc3[m][0][i] + acc3[m][1][i];
            float q = acc3[m][0][i] * acc3[m][0][i] + acc3[m][1][i] * acc3[m][1][i];
            s += __shfl_xor(s, 1); s += __shfl_xor(s, 2); s += __shfl_xor(s, 4); s += __shfl_xor(s, 8);
            q += __shfl_xor(q, 1); q += __shfl_xor(q, 2); q += __shfl_xor(q, 4); q += __shfl_xor(q, 8);
            if (lr == 0) { redS2[wc * ROWS + lrow[m][i]] = s; redQ2[wc * ROWS + lrow[m][i]] = q; }
        }
    __syncthreads();                                           // B6

    // ---- P7: issue Wq/Wk/Wv DMA (smW, smF dead); LN2 finalize + h stores ----
    if (doQKV) {
        stage_lds<128, 4>(smW,         Wq, t);
        stage_lds<128, 4>(smW + 32768, Wk, t);
        stage_lds<128, 4>(smF,         Wv, t);
    }
    {
        float gam[2] = { g2v[gcol[0]], g2v[gcol[1]] };
        float bet[2] = { b2v[gcol[0]], b2v[gcol[1]] };
#pragma unroll
        for (int m = 0; m < 3; ++m)
#pragma unroll
            for (int i = 0; i < 4; ++i) {
                int lw = lrow[m][i];
                float s = redS2[lw] + redS2[ROWS + lw] + redS2[2 * ROWS + lw] + redS2[3 * ROWS + lw];
                float q = redQ2[lw] + redQ2[ROWS + lw] + redQ2[2 * ROWS + lw] + redQ2[3 * ROWS + lw];
                float mean = s * 0.0078125f;
                float var  = q * 0.0078125f - mean * mean;
                float rstd = rsqrtf(var + 1e-5f);
                int row = n0 + lw;
#pragma unroll
                for (int n = 0; n < 2; ++n) {
                    float o = (acc3[m][n][i] - mean) * rstd * gam[n] + bet[n];
                    acc3[m][n][i] = o;
                    if (row < NN) {
                        hres[(size_t)row * DM + gcol[n]] = __float2bfloat16(o);
                        if (hout_f) hout_f[(size_t)row * DM + gcol[n]] = o;
                    }
                }
            }
    }
    if (!doQKV) return;
    __syncthreads();                                           // B7

    // ---- P8: h_new -> smA (stats dead) ----
#pragma unroll
    for (int m = 0; m < 3; ++m)
#pragma unroll
        for (int i = 0; i < 4; ++i) {
            int rw = lrow[m][i];
#pragma unroll
            for (int n = 0; n < 2; ++n)
                *(unsigned short*)(smA + rw * 256 + ((gcol[n] * 2) ^ ((rw & 7) << 4))) = f2bu(acc3[m][n][i]);
        }
    __syncthreads();                                           // B8

    // ---- P9: GEMM_Q + GEMM_K + GEMM_V ----
    {
        f4 aq[3][2];
#pragma unroll
        for (int m = 0; m < 3; ++m) { aq[m][0] = (f4){0,0,0,0}; aq[m][1] = (f4){0,0,0,0}; }
        mm2<3, 2, 4>(smA, 256, smW, 256, wr, wc, lr, lk, aq);
        float b_[2] = { bqv[gcol[0]], bqv[gcol[1]] };
#pragma unroll
        for (int m = 0; m < 3; ++m)
#pragma unroll
            for (int i = 0; i < 4; ++i) {
                int row = n0 + lrow[m][i];
                if (row < NN)
#pragma unroll
                    for (int n = 0; n < 2; ++n)
                        Qo[(size_t)row * DM + gcol[n]] = __float2bfloat16(aq[m][n][i] + b_[n]);
            }
    }
    {
        f4 ak[3][2];
#pragma unroll
        for (int m = 0; m < 3; ++m) { ak[m][0] = (f4){0,0,0,0}; ak[m][1] = (f4){0,0,0,0}; }
        mm2<3, 2, 4>(smA, 256, smW + 32768, 256, wr, wc, lr, lk, ak);
        float b_[2] = { bkv[gcol[0]], bkv[gcol[1]] };
#pragma unroll
        for (int m = 0; m < 3; ++m)
#pragma unroll
            for (int i = 0; i < 4; ++i) {
                int row = n0 + lrow[m][i];
                if (row < NN)
#pragma unroll
                    for (int n = 0; n < 2; ++n)
                        Ko[(size_t)row * DM + gcol[n]] = f2fp8(ak[m][n][i] + b_[n]);
            }
    }
    {
        f4 av_[3][2];
#pragma unroll
        for (int m = 0; m < 3; ++m) { av_[m][0] = (f4){0,0,0,0}; av_[m][1] = (f4){0,0,0,0}; }
        mm2<3, 2, 4>(smA, 256, smF, 256, wr, wc, lr, lk, av_);
        float b_[2] = { bvv[gcol[0]], bvv[gcol[1]] };
#pragma unroll
        for (int m = 0; m < 3; ++m)
#pragma unroll
            for (int i = 0; i < 4; ++i) {
                int row = n0 + lrow[m][i];
                if (row < NN)
#pragma unroll
                    for (int n = 0; n < 2; ++n)
                        Vo[(size_t)row * DM + gcol[n]] = f2fp8(av_[m][n][i] + b_[n]);
            }
    }
}

// ---------------- edge attention: fp8 K/V, 8 lanes per edge (one head per lane) ----------------
__global__ __launch_bounds__(256)
void attn_k(const bf16* __restrict__ Q, const unsigned char* __restrict__ K8,
            const unsigned char* __restrict__ V8, const int* __restrict__ row_ptr,
            const int* __restrict__ csr, bf16* __restrict__ out)
{
    int lane = threadIdx.x & 63;
    int n = blockIdx.x * 4 + (threadIdx.x >> 6);
    int g = lane >> 3, sub = lane & 7;
    const uint4* K4 = (const uint4*)K8;
    const uint4* V4 = (const uint4*)V8;
    float q[16];
    {
        const uint4* Q4 = (const uint4*)Q;
        uint4 qa = Q4[n * 16 + sub * 2];
        uint4 qb = Q4[n * 16 + sub * 2 + 1];
        up8(qa, q); up8(qb, q + 8);
    }
    int e0 = row_ptr[n], e1 = row_ptr[n + 1];
    float acc[16];
#pragma unroll
    for (int j = 0; j < 16; ++j) acc[j] = 0.f;
    float zacc = 0.f;

    int sA = (e0 + g < e1) ? csr[e0 + g] : 0;
    uint4 k0 = K4[(size_t)sA * 8 + sub];
    uint4 v0 = V4[(size_t)sA * 8 + sub];
    int sB = (e0 + 8 + g < e1) ? csr[e0 + 8 + g] : 0;
    uint4 k1 = K4[(size_t)sB * 8 + sub];
    uint4 v1 = V4[(size_t)sB * 8 + sub];
    for (int base = e0; base < e1; base += 8) {
        int en = base + 16 + g;
        int s2 = (en < e1) ? csr[en] : 0;
        uint4 k2 = K4[(size_t)s2 * 8 + sub];      // 2-deep prefetch
        uint4 v2 = V4[(size_t)s2 * 8 + sub];
        float kf[16];
        fp8x4(k0.x, kf); fp8x4(k0.y, kf + 4); fp8x4(k0.z, kf + 8); fp8x4(k0.w, kf + 12);
        float p = 0.f;
#pragma unroll
        for (int j = 0; j < 16; ++j) p = fmaf(q[j], kf[j], p);
        float sc = __expf(fminf(fmaxf(p * 0.25f, -10.f), 10.f)) * 0.5f;
        if (base + g >= e1) sc = 0.f;
        float vf[16];
        fp8x4(v0.x, vf); fp8x4(v0.y, vf + 4); fp8x4(v0.z, vf + 8); fp8x4(v0.w, vf + 12);
#pragma unroll
        for (int j = 0; j < 16; ++j) acc[j] = fmaf(sc, vf[j], acc[j]);
        zacc += sc;
        k0 = k1; v0 = v1; k1 = k2; v1 = v2;
    }
#pragma unroll
    for (int j = 0; j < 16; ++j) {
        acc[j] += __shfl_xor(acc[j], 8);
        acc[j] += __shfl_xor(acc[j], 16);
        acc[j] += __shfl_xor(acc[j], 32);
    }
    zacc += __shfl_xor(zacc, 8);
    zacc += __shfl_xor(zacc, 16);
    zacc += __shfl_xor(zacc, 32);
    float inv = 1.f / (zacc + 1e-6f);
    if (g == 0) {
        uint4 o1, o2;
        o1.x = pk2(acc[0] * inv, acc[1] * inv);
        o1.y = pk2(acc[2] * inv, acc[3] * inv);
        o1.z = pk2(acc[4] * inv, acc[5] * inv);
        o1.w = pk2(acc[6] * inv, acc[7] * inv);
        o2.x = pk2(acc[8] * inv, acc[9] * inv);
        o2.y = pk2(acc[10] * inv, acc[11] * inv);
        o2.z = pk2(acc[12] * inv, acc[13] * inv);
        o2.w = pk2(acc[14] * inv, acc[15] * inv);
        ((uint4*)out)[n * 16 + sub * 2] = o1;
        ((uint4*)out)[n * 16 + sub * 2 + 1] = o2;
    }
}

// ---------------- host side ----------------
static inline void g1(hipStream_t st, const bf16* A, const bf16* A2, const bf16* W,
                      const float* bia, float* Cf, bf16* Cb, int N, int K, int M, int post)
{
    dim3 grid((N + 63) / 64, M / 128, 1);
    gemm_k<<<grid, 256, 0, st>>>(A, A2, W, nullptr, nullptr, bia, nullptr, nullptr,
                                 Cf, Cb, nullptr, nullptr, nullptr, nullptr, N, K, M, post);
}

static inline void g3(hipStream_t st, const bf16* A,
                      const bf16* W0, const float* b0, bf16* C0,
                      const bf16* W1, const float* b1, unsigned char* C1,
                      const bf16* W2, const float* b2, unsigned char* C2,
                      int N, int K, int M)
{
    dim3 grid((N + 63) / 64, M / 128, 3);
    gemm_k<<<grid, 256, 0, st>>>(A, nullptr, W0, W1, W2, b0, b1, b2,
                                 nullptr, C0, nullptr, nullptr, C1, C2, N, K, M, 0);
}

extern "C" void kernel_launch(void* const* d_in, const int* in_sizes, int n_in,
                              void* d_out, int out_size, void* d_ws, size_t ws_size,
                              hipStream_t stream)
{
    const float* x    = (const float*)d_in[0];
    const float* Iin  = (const float*)d_in[1];
    const int*   src  = (const int*)d_in[2];
    const int*   dst  = (const int*)d_in[3];
    const float* Wemb = (const float*)d_in[4];
    const float* Wq   = (const float*)d_in[5];  const float* bq  = (const float*)d_in[6];
    const float* Wk   = (const float*)d_in[7];  const float* bk  = (const float*)d_in[8];
    const float* Wv   = (const float*)d_in[9];  const float* bv  = (const float*)d_in[10];
    const float* Wi   = (const float*)d_in[11]; const float* bi  = (const float*)d_in[12];
    const float* Wo   = (const float*)d_in[13]; const float* bo  = (const float*)d_in[14];
    const float* g1g  = (const float*)d_in[15]; const float* be1 = (const float*)d_in[16];
    const float* g2g  = (const float*)d_in[17]; const float* be2 = (const float*)d_in[18];
    const float* Wf1  = (const float*)d_in[19]; const float* bf1 = (const float*)d_in[20];
    const float* Wf2  = (const float*)d_in[21]; const float* bf2 = (const float*)d_in[22];
    const float* Wm1  = (const float*)d_in[23]; const float* bm1 = (const float*)d_in[24];
    const float* Wm2  = (const float*)d_in[25]; const float* bm2 = (const float*)d_in[26];

    const size_t NF = (size_t)NN * DM;          // 2,560,000
    bf16* B      = (bf16*)d_ws;
    bf16* h_b    = B;                           // bf16 residual stream (in-place updated)
    bf16* Qb     = B + NF;
    unsigned char* K8 = (unsigned char*)(B + 2 * NF);   // N x 128 fp8
    unsigned char* V8 = (unsigned char*)(B + 3 * NF);
    bf16* attn_b = B + 4 * NF;
    bf16* Iw_b   = B + 5 * NF;
    bf16* wts    = B + 6 * NF;
    bf16* Wemb_b = wts;                 // 32768
    bf16* Wq_b   = wts + 32768;         // 16384
    bf16* Wk_b   = Wq_b + 16384;
    bf16* Wv_b   = Wk_b + 16384;
    bf16* Wo_b   = Wv_b + 16384;
    bf16* Wi_b   = Wo_b + 16384;        // 8192
    bf16* Wf1_b  = Wi_b + 8192;         // 32768
    bf16* Wf2_b  = Wf1_b + 32768;       // 32768
    bf16* Wm1_b  = Wf2_b + 32768;       // 16384
    bf16* Wm2_b  = Wm1_b + 16384;       // 32768
    bf16* wend   = Wm2_b + 32768;
    bf16* x_b    = Qb;                  // N x 256 (spans Qb + K8 slots), dead after embed
    bf16* Iin_b  = B + 3 * NF;          // N x 64 in V8 slot, dead before QKV0
    bf16* tmp_b  = Qb;                  // head mid (N x 128), Qb dead after last attn
    int* ib      = (int*)wend;
    int* cnt     = ib;
    int* cnt2    = ib + NN;
    int* row_ptr = ib + 2 * NN;
    int* csr     = ib + 3 * NN + 1;
    int* part    = csr + NE;
    int* bsum    = part + NN;
    int* carry   = bsum + 32;
    int* total   = carry + 32;

    // ---- CSR build (once per call) ----
    hipMemsetAsync(cnt,  0, NN * sizeof(int), stream);
    hipMemsetAsync(cnt2, 0, NN * sizeof(int), stream);
    hist_k<<<(NE + 255) / 256, 256, 0, stream>>>(dst, cnt, NE);
    const int nsb = (NN + 1023) / 1024;
    scan1_k<<<nsb, 1024, 0, stream>>>(cnt, part, bsum, NN);
    scan2_k<<<1, 64, 0, stream>>>(bsum, carry, nsb, total);
    scan3_k<<<(NN + 256) / 256, 256, 0, stream>>>(part, carry, total, row_ptr, NN);
    scatter_k<<<(NE + 255) / 256, 256, 0, stream>>>(src, dst, row_ptr, cnt2, csr, NE);

    // ---- batched f32->bf16 conversion of x, I, and all weights ----
    Cvt c;
    c.s[0] = x;    c.d[0] = x_b;    c.n[0] = NN * DIN;
    c.s[1] = Iin;  c.d[1] = Iin_b;  c.n[1] = NN * 64;
    c.s[2] = Wemb; c.d[2] = Wemb_b; c.n[2] = 32768;
    c.s[3] = Wq;   c.d[3] = Wq_b;   c.n[3] = 16384;
    c.s[4] = Wk;   c.d[4] = Wk_b;   c.n[4] = 16384;
    c.s[5] = Wv;   c.d[5] = Wv_b;   c.n[5] = 16384;
    c.s[6] = Wo;   c.d[6] = Wo_b;   c.n[6] = 16384;
    c.s[7] = Wi;   c.d[7] = Wi_b;   c.n[7] = 8192;
    c.s[8] = Wf1;  c.d[8] = Wf1_b;  c.n[8] = 32768;
    c.s[9] = Wf2;  c.d[9] = Wf2_b;  c.n[9] = 32768;
    c.s[10] = Wm1; c.d[10] = Wm1_b; c.n[10] = 16384;
    c.s[11] = Wm2; c.d[11] = Wm2_b; c.n[11] = 32768;
    cvt_many_k<<<dim3(640, 12), 256, 0, stream>>>(c);

    // ---- prologue: embed, Iw, first-layer QKV (K/V straight to fp8) ----
    g1(stream, x_b,   nullptr, Wemb_b, nullptr, nullptr, h_b, NN, DIN, DM, 0);
    g1(stream, Iin_b, nullptr, Wi_b, bi, nullptr, Iw_b, NN, 64, DM, 0);
    g3(stream, h_b, Wq_b, bq, Qb, Wk_b, bk, K8, Wv_b, bv, V8, NN, DM, DM);

    // ---- 10 shared-weight layers: attn + mega-fused ----
    const int nblk = (NN + ROWS - 1) / ROWS;    // 209 <= 256 -> single round
    for (int l = 0; l < 10; ++l) {
        attn_k<<<NN / 4, 256, 0, stream>>>(Qb, K8, V8, row_ptr, csr, attn_b);
        layer_k<<<nblk, 512, 139264, stream>>>(
            attn_b, Iw_b, h_b, (l == 9) ? (float*)d_out : nullptr,
            Qb, K8, V8, (l < 9) ? 1 : 0,
            Wo_b, bo, Wf1_b, bf1, Wf2_b, bf2,
            Wq_b, bq, Wk_b, bk, Wv_b, bv,
            g1g, be1, g2g, be2);
    }

    // ---- reconstruction head ----
    g1(stream, h_b, nullptr, Wm1_b, bm1, nullptr, tmp_b, NN, DM, DM, 2);   // selu
    float* xhat = (float*)d_out + NF;
    g1(stream, tmp_b, nullptr, Wm2_b, bm2, xhat, nullptr, NN, DM, DIN, 0);
}